// Round 9
// baseline (513.537 us; speedup 1.0000x reference)
//
#include <hip/hip_runtime.h>

#define BB 8
#define TT 512
#define DD 1024
#define HH 16
#define DKK 64
#define SS 1023

typedef unsigned short u16;
typedef __attribute__((ext_vector_type(8))) short bf16x8;
typedef __attribute__((ext_vector_type(4))) float f32x4;

#define MFMA16(a, b, c) __builtin_amdgcn_mfma_f32_16x16x32_bf16((a), (b), (c), 0, 0, 0)

// Wave-local LDS fence: all LDS traffic in attn_mfma is per-wave (wls[w]),
// so a block barrier is never needed -- just drain this wave's DS queue and
// pin the schedule (guide rule #18).
#define WAVE_SYNC() do { asm volatile("s_waitcnt lgkmcnt(0)" ::: "memory"); __builtin_amdgcn_sched_barrier(0); } while (0)

__device__ __forceinline__ float us2f(u16 u) {
    unsigned int x = ((unsigned int)u) << 16;
    return __uint_as_float(x);
}
__device__ __forceinline__ u16 f2us(float f) {
    unsigned int x = __float_as_uint(f);
    unsigned int lsb = (x >> 16) & 1u;
    x += 0x7fffu + lsb;
    return (u16)(x >> 16);
}
__device__ __forceinline__ bf16x8 cvt8(const float* p) {
    float4 f1 = *(const float4*)p;
    float4 f2 = *(const float4*)(p + 4);
    bf16x8 r;
    r[0] = (short)f2us(f1.x); r[1] = (short)f2us(f1.y);
    r[2] = (short)f2us(f1.z); r[3] = (short)f2us(f1.w);
    r[4] = (short)f2us(f2.x); r[5] = (short)f2us(f2.y);
    r[6] = (short)f2us(f2.z); r[7] = (short)f2us(f2.w);
    return r;
}

// flags[0] = 1 if float buffers are bf16, 0 if f32
// flags[1] = 1 if mask is int32, 0 if int8/bool
__global__ void detect_kernel(const u16* __restrict__ w,
                              const unsigned int* __restrict__ mask,
                              int* __restrict__ flags) {
    if (threadIdx.x == 0 && blockIdx.x == 0) {
        int plaus = 0;
        for (int i = 0; i < 256; i++) {
            u16 hw = w[i];
            int e = (hw >> 7) & 0xFF;
            if (e == 0 || (e >= 87 && e <= 131)) plaus++;
        }
        flags[0] = (plaus >= 205) ? 1 : 0;
        int ok = 1;
        for (int i = 0; i < 64; i++) if (mask[i] > 1u) ok = 0;
        flags[1] = ok;
    }
}

// Pack mask into bits: packed[(b*T + t)*16 + g], bit k = mask[b][t][k*16 + g].
__global__ __launch_bounds__(256) void pack_mask(const void* __restrict__ mask,
                                                 unsigned int* __restrict__ packed,
                                                 const int* __restrict__ flags) {
    const int idx = blockIdx.x * 256 + threadIdx.x;   // 8*512*16 = 65536 words
    const int g = idx & 15;
    const size_t bt = (size_t)(idx >> 4);
    unsigned int bits = 0;
    if (flags[1]) {
        const int* mp = (const int*)mask + bt * TT + g;
        #pragma unroll
        for (int k = 0; k < 32; k++) if (mp[k * 16] != 0) bits |= (1u << k);
    } else {
        const signed char* mp = (const signed char*)mask + bt * TT + g;
        #pragma unroll
        for (int k = 0; k < 32; k++) if (mp[k * 16] != 0) bits |= (1u << k);
    }
    packed[idx] = bits;
}

// ---------------- 128x128-tile MFMA GEMM: C[i,n] = sum_k A[i,k]*W[n,k] (+bias)
// 4 waves in 2x2; each wave owns 64x64 = 4x4 frags of 16x16x32.
// 16 MFMA + 8 ds_read_b128 per K-step per wave (m93-class structure).
// OMODE 0: qkv scatter (q->f32 [bh][t][d], k->bf16 [bh][t][d], v->bf16 TRANSPOSED [bh][d][t])
// OMODE 1: pos scatter bf16 [h][s'][d], guard i<M (row clamp on load)
// OMODE 2: A from ctx f32 (qT head-major), out [M,N] + bias, NT stores (never re-read)
template<int OMODE>
__global__ __launch_bounds__(256) void gemm_mfma(
    const void* __restrict__ Av, const void* __restrict__ Wv,
    const void* __restrict__ bias, const int* __restrict__ flags,
    float* __restrict__ qT, u16* __restrict__ kB, u16* __restrict__ vB,
    u16* __restrict__ pB, void* __restrict__ oout, int M, int N, int K)
{
    const bool isbf = (flags[0] != 0);
    __shared__ u16 As[128][40];   // [m][k 0..31], +8 pad
    __shared__ u16 Bs[128][40];
    const int tid = threadIdx.x;
    const int w = tid >> 6, lane = tid & 63;
    const int quad = lane >> 4, l16 = lane & 15;
    const int wr = w >> 1, wc = w & 1;
    const int bn = blockIdx.x * 128, bm = blockIdx.y * 128;
    const int r0 = tid >> 2;            // 0..63 staging row (and +64)
    const int koff = (tid & 3) * 8;     // 0,8,16,24

    f32x4 acc[4][4];
    #pragma unroll
    for (int m = 0; m < 4; m++)
        #pragma unroll
        for (int n = 0; n < 4; n++) {
            acc[m][n][0] = 0.f; acc[m][n][1] = 0.f;
            acc[m][n][2] = 0.f; acc[m][n][3] = 0.f;
        }

    for (int k0 = 0; k0 < K; k0 += 32) {
        int ar0 = bm + r0, ar1 = bm + r0 + 64;
        if (OMODE == 1) { ar0 = min(ar0, M - 1); ar1 = min(ar1, M - 1); }
        const int br0 = bn + r0, br1 = bn + r0 + 64;

        bf16x8 a0, a1, b0, b1;
        if (OMODE == 2) {
            const int kk = k0 + koff;
            const float* ap0 = qT + (((size_t)((ar0 >> 9) * HH + (kk >> 6)) * TT + (ar0 & 511)) << 6) + (kk & 63);
            const float* ap1 = qT + (((size_t)((ar1 >> 9) * HH + (kk >> 6)) * TT + (ar1 & 511)) << 6) + (kk & 63);
            a0 = cvt8(ap0); a1 = cvt8(ap1);
        } else if (isbf) {
            a0 = *(const bf16x8*)((const u16*)Av + (size_t)ar0 * K + k0 + koff);
            a1 = *(const bf16x8*)((const u16*)Av + (size_t)ar1 * K + k0 + koff);
        } else {
            a0 = cvt8((const float*)Av + (size_t)ar0 * K + k0 + koff);
            a1 = cvt8((const float*)Av + (size_t)ar1 * K + k0 + koff);
        }
        if (isbf) {
            b0 = *(const bf16x8*)((const u16*)Wv + (size_t)br0 * K + k0 + koff);
            b1 = *(const bf16x8*)((const u16*)Wv + (size_t)br1 * K + k0 + koff);
        } else {
            b0 = cvt8((const float*)Wv + (size_t)br0 * K + k0 + koff);
            b1 = cvt8((const float*)Wv + (size_t)br1 * K + k0 + koff);
        }

        __syncthreads();
        *(bf16x8*)&As[r0][koff] = a0;
        *(bf16x8*)&As[r0 + 64][koff] = a1;
        *(bf16x8*)&Bs[r0][koff] = b0;
        *(bf16x8*)&Bs[r0 + 64][koff] = b1;
        __syncthreads();

        bf16x8 af[4], bf[4];
        #pragma unroll
        for (int m = 0; m < 4; m++)
            af[m] = *(const bf16x8*)&As[wr * 64 + m * 16 + l16][quad * 8];
        #pragma unroll
        for (int n = 0; n < 4; n++)
            bf[n] = *(const bf16x8*)&Bs[wc * 64 + n * 16 + l16][quad * 8];
        #pragma unroll
        for (int m = 0; m < 4; m++)
            #pragma unroll
            for (int n = 0; n < 4; n++)
                acc[m][n] = MFMA16(af[m], bf[n], acc[m][n]);
    }

    #pragma unroll
    for (int m = 0; m < 4; m++)
        #pragma unroll
        for (int nn = 0; nn < 4; nn++)
            #pragma unroll
            for (int rr = 0; rr < 4; rr++) {
                const int i = bm + wr * 64 + m * 16 + quad * 4 + rr;
                const int n = bn + wc * 64 + nn * 16 + l16;
                float val = acc[m][nn][rr];
                if (OMODE == 0) {
                    val += isbf ? us2f(((const u16*)bias)[n]) : ((const float*)bias)[n];
                    const int sec = n >> 10, w_ = n & 1023;
                    const int h_ = w_ >> 6, d_ = w_ & 63;
                    const size_t bh_ = (size_t)((i >> 9) * HH + h_);
                    const int t_ = i & 511;
                    if (sec == 0) qT[((bh_ * TT + t_) << 6) + d_] = val;
                    else if (sec == 1) kB[((bh_ * TT + t_) << 6) + d_] = f2us(val);
                    else vB[((bh_ * DKK + d_) << 9) + t_] = f2us(val);
                } else if (OMODE == 1) {
                    if (i < M) {
                        const int h_ = n >> 6, d_ = n & 63;
                        pB[((size_t)(h_ * 1024 + i) << 6) + d_] = f2us(val);
                    }
                } else {
                    val += isbf ? us2f(((const u16*)bias)[n]) : ((const float*)bias)[n];
                    if (isbf) __builtin_nontemporal_store(f2us(val), &((u16*)oout)[(size_t)i * N + n]);
                    else      __builtin_nontemporal_store(val, &((float*)oout)[(size_t)i * N + n]);
                }
            }
}

// ---------------- MFMA attention: block = (t-tile 64, h, b), 4 waves x 16 rows
// All LDS is per-wave -> NO block barriers anywhere (wave-local lgkmcnt only).
// Weights output (128 MB f32) is write-only for the GPU -> NON-TEMPORAL stores
// so the stream doesn't evict K/V/P from L2/L3 (FETCH was 2.6x the unique bytes).
__global__ __launch_bounds__(256) void attn_mfma(
    float* __restrict__ qT, const u16* __restrict__ kB, const u16* __restrict__ vB,
    const u16* __restrict__ pB, const void* __restrict__ posu,
    const void* __restrict__ posv, const unsigned int* __restrict__ pmask,
    void* __restrict__ d_out, const int* __restrict__ flags)
{
    const int t0 = blockIdx.x << 6;
    const int h = blockIdx.y, b = blockIdx.z;
    const int tid = threadIdx.x;
    const int w = tid >> 6, lane = tid & 63;
    const int quad = lane >> 4, l16 = lane & 15;
    const bool isbf = (flags[0] != 0);
    const size_t bh = (size_t)b * HH + h;

    __shared__ u16 wls[4][16][520];          // per-wave weights tile (also aliased as bd f32)
    u16* wme = &wls[w][0][0];
    float* bdw = (float*)wme;                // [16][84] f32 scratch, per-wave

    // ---- packed mask words (4 coalesced u32 loads/thread, hoisted early)
    const int trow = t0 + w * 16 + quad * 4;
    unsigned int mrow[4];
    #pragma unroll
    for (int r = 0; r < 4; r++)
        mrow[r] = pmask[((size_t)(b * TT + trow + r) << 4) + l16];

    // ---- A fragments q_u, q_v (prescaled by 0.125 so scores come out /8)
    const int myrow = t0 + w * 16 + l16;
    const float* qrow = qT + ((bh * TT + myrow) << 6);
    bf16x8 aU[2], aV[2];
    #pragma unroll
    for (int f = 0; f < 2; f++) {
        const int d0 = f * 32 + quad * 8;
        float q8[8], pu8[8], pv8[8];
        *(float4*)&q8[0] = *(const float4*)(qrow + d0);
        *(float4*)&q8[4] = *(const float4*)(qrow + d0 + 4);
        if (isbf) {
            const u16* puP = (const u16*)posu + h * 64 + d0;
            const u16* pvP = (const u16*)posv + h * 64 + d0;
            #pragma unroll
            for (int j = 0; j < 8; j++) { pu8[j] = us2f(puP[j]); pv8[j] = us2f(pvP[j]); }
        } else {
            const float* puP = (const float*)posu + h * 64 + d0;
            const float* pvP = (const float*)posv + h * 64 + d0;
            #pragma unroll
            for (int j = 0; j < 8; j++) { pu8[j] = puP[j]; pv8[j] = pvP[j]; }
        }
        #pragma unroll
        for (int j = 0; j < 8; j++) {
            aU[f][j] = (short)f2us((q8[j] + pu8[j]) * 0.125f);
            aV[f][j] = (short)f2us((q8[j] + pv8[j]) * 0.125f);
        }
    }

    // ---- AC scores: S[32] covers 512 cols (s)
    f32x4 S[32];
    #pragma unroll
    for (int ct = 0; ct < 32; ct++) { S[ct][0] = 0.f; S[ct][1] = 0.f; S[ct][2] = 0.f; S[ct][3] = 0.f; }
    const u16* kbase = kB + ((bh * TT) << 6) + quad * 8;
    #pragma unroll
    for (int ct = 0; ct < 32; ct++) {
        const u16* kp = kbase + ((size_t)(ct * 16 + l16) << 6);
        bf16x8 b0 = *(const bf16x8*)kp;
        bf16x8 b1 = *(const bf16x8*)(kp + 32);
        S[ct] = MFMA16(aU[0], b0, S[ct]);
        S[ct] = MFMA16(aU[1], b1, S[ct]);
    }

    // ---- BD: 8 chunks of 64 cols; per-wave 16x80 tile via LDS, skewed gather
    const u16* pbaseh = pB + ((size_t)h << 16);  // h stride = 1024 rows * 64
    for (int g = 0; g < 8; g++) {
        const int pb = g * 64 - t0 + 496 - w * 16;  // P row for c_local=0 (>=0, <=944)
        #pragma unroll
        for (int c5 = 0; c5 < 5; c5++) {
            const u16* pp = pbaseh + ((size_t)(pb + c5 * 16 + l16) << 6) + quad * 8;
            bf16x8 b0 = *(const bf16x8*)pp;
            bf16x8 b1 = *(const bf16x8*)(pp + 32);
            f32x4 c; c[0] = 0.f; c[1] = 0.f; c[2] = 0.f; c[3] = 0.f;
            c = MFMA16(aV[0], b0, c);
            c = MFMA16(aV[1], b1, c);
            #pragma unroll
            for (int r = 0; r < 4; r++)
                bdw[(quad * 4 + r) * 84 + c5 * 16 + l16] = c[r];
        }
        WAVE_SYNC();   // per-wave write->read visibility; WAR handled by in-order DS
        #pragma unroll
        for (int f = 0; f < 4; f++) {
            const int sc = f * 16 + l16;
            #pragma unroll
            for (int r = 0; r < 4; r++) {
                const int local = quad * 4 + r;
                // bd[local][sc + 15 - local]
                S[g * 4 + f][r] += bdw[local * 83 + sc + 15];
            }
        }
    }

    // ---- mask (bit test, no memory traffic)
    #pragma unroll
    for (int ct = 0; ct < 32; ct++) {
        #pragma unroll
        for (int r = 0; r < 4; r++) {
            if (!(mrow[r] & (1u << ct))) S[ct][r] = -100000.0f;
        }
    }

    // ---- softmax (rows live across 16 lanes of this quad)
    float mx[4] = {-3.0e38f, -3.0e38f, -3.0e38f, -3.0e38f};
    float sm[4] = {0.f, 0.f, 0.f, 0.f};
    #pragma unroll
    for (int ct = 0; ct < 32; ct++)
        #pragma unroll
        for (int r = 0; r < 4; r++) mx[r] = fmaxf(mx[r], S[ct][r]);
    #pragma unroll
    for (int r = 0; r < 4; r++)
        #pragma unroll
        for (int off = 1; off < 16; off <<= 1) mx[r] = fmaxf(mx[r], __shfl_xor(mx[r], off, 64));
    #pragma unroll
    for (int ct = 0; ct < 32; ct++)
        #pragma unroll
        for (int r = 0; r < 4; r++) {
            float e = __expf(S[ct][r] - mx[r]);
            S[ct][r] = e;
            sm[r] += e;
        }
    #pragma unroll
    for (int r = 0; r < 4; r++) {
        #pragma unroll
        for (int off = 1; off < 16; off <<= 1) sm[r] += __shfl_xor(sm[r], off, 64);
        sm[r] = 1.0f / sm[r];
    }

    // ---- weights: stage per-wave LDS tile (A-operand layout) + NT global store
    const size_t wbase = (size_t)BB * TT * DD + (((bh * TT + trow)) << 9) + l16;
    #pragma unroll
    for (int ct = 0; ct < 32; ct++) {
        #pragma unroll
        for (int r = 0; r < 4; r++) {
            const float wv = S[ct][r] * sm[r];
            wls[w][quad * 4 + r][ct * 16 + l16] = f2us(wv);
            if (!isbf) __builtin_nontemporal_store(wv, &((float*)d_out)[wbase + ((size_t)r << 9) + ct * 16]);
        }
    }
    WAVE_SYNC();
    if (isbf) {
        u16* wout = (u16*)d_out + (size_t)BB * TT * DD + ((bh * TT + t0 + w * 16) << 9);
        const int lane8 = lane * 8;
        #pragma unroll
        for (int rr = 0; rr < 16; rr++) {
            bf16x8 vv = *(const bf16x8*)&wls[w][rr][lane8];
            __builtin_nontemporal_store(vv, (bf16x8*)(wout + ((size_t)rr << 9) + lane8));
        }
    }

    // ---- PV: ctx[16x64] = W[16x512] x V[512x64], V transposed [bh][d][s]
    f32x4 Cv[4];
    #pragma unroll
    for (int i = 0; i < 4; i++) { Cv[i][0] = 0.f; Cv[i][1] = 0.f; Cv[i][2] = 0.f; Cv[i][3] = 0.f; }
    const u16* vb0 = vB + ((bh * DKK) << 9) + quad * 8;
    #pragma unroll
    for (int ks = 0; ks < 16; ks++) {
        bf16x8 aw = *(const bf16x8*)&wls[w][l16][ks * 32 + quad * 8];
        #pragma unroll
        for (int ctd = 0; ctd < 4; ctd++) {
            const u16* vp = vb0 + ((size_t)(ctd * 16 + l16) << 9) + ks * 32;
            bf16x8 bv = *(const bf16x8*)vp;
            Cv[ctd] = MFMA16(aw, bv, Cv[ctd]);
        }
    }
    // ctx overwrites this block's own q rows (read-complete); re-read by gemm<2> -> cached stores
    float* crow = qT + ((bh * TT + trow) << 6) + l16;
    #pragma unroll
    for (int ctd = 0; ctd < 4; ctd++)
        #pragma unroll
        for (int r = 0; r < 4; r++)
            crow[(r << 6) + ctd * 16] = Cv[ctd][r];
}

extern "C" void kernel_launch(void* const* d_in, const int* in_sizes, int n_in,
                              void* d_out, int out_size, void* d_ws, size_t ws_size,
                              hipStream_t stream)
{
    const void* x    = d_in[0];
    const void* mask = d_in[1];
    const void* pos  = d_in[2];
    const void* Wqkv = d_in[3];
    const void* bqkv = d_in[4];
    const void* Wpos = d_in[5];
    const void* posu = d_in[6];
    const void* posv = d_in[7];
    const void* Wout = d_in[8];
    const void* bout = d_in[9];

    char* ws = (char*)d_ws;
    float* qT    = (float*)(ws + 0);                 // [B,H,T,64] f32 16 MiB (ctx reuses)
    u16*   kB    = (u16*)(ws + 16777216);            // [B,H,T,64] bf16 8 MiB
    u16*   vB    = (u16*)(ws + 25165824);            // [B,H,64,T] bf16 8 MiB (transposed)
    u16*   pB    = (u16*)(ws + 33554432);            // [H,1024,64] bf16 2 MiB (row 1023 = pad)
    int*   flags = (int*)(ws + 35651584);
    unsigned int* pmask = (unsigned int*)(ws + 35655680);  // [B,T,16] u32, 256 KiB

    detect_kernel<<<1, 64, 0, stream>>>((const u16*)Wqkv, (const unsigned int*)mask, flags);
    pack_mask<<<dim3(256), 256, 0, stream>>>(mask, pmask, flags);

    // 1) qkv = x @ Wqkv^T + bqkv -> q(f32), k(bf16), v(bf16 transposed)
    gemm_mfma<0><<<dim3(24, 32), 256, 0, stream>>>(
        x, Wqkv, bqkv, flags, qT, kB, vB, pB, nullptr, BB * TT, 3 * DD, DD);

    // 2) p = pos @ Wpos^T -> bf16 [H,1024,64]
    gemm_mfma<1><<<dim3(8, 8), 256, 0, stream>>>(
        pos, Wpos, nullptr, flags, qT, kB, vB, pB, nullptr, SS, DD, DD);

    // 3) attention: weights -> d_out + B*T*D (NT), ctx -> qT
    attn_mfma<<<dim3(8, HH, BB), 256, 0, stream>>>(
        qT, kB, vB, pB, posu, posv, pmask, d_out, flags);

    // 4) out = ctx @ Wout^T + bout (NT stores)
    gemm_mfma<2><<<dim3(8, 32), 256, 0, stream>>>(
        nullptr, Wout, bout, flags, qT, kB, vB, pB, d_out, BB * TT, DD, DD);
}

// Round 12
// 498.429 us; speedup vs baseline: 1.0303x; 1.0303x over previous
//
#include <hip/hip_runtime.h>

#define BB 8
#define TT 512
#define DD 1024
#define HH 16
#define DKK 64
#define SS 1023

typedef unsigned short u16;
typedef __attribute__((ext_vector_type(8))) short bf16x8;
typedef __attribute__((ext_vector_type(4))) float f32x4;

#define MFMA16(a, b, c) __builtin_amdgcn_mfma_f32_16x16x32_bf16((a), (b), (c), 0, 0, 0)

// Wave-local LDS fence: all LDS traffic in attn_mfma is per-wave (wls[w]),
// so a block barrier is never needed -- just drain this wave's DS queue and
// pin the schedule (guide rule #18).
#define WAVE_SYNC() do { asm volatile("s_waitcnt lgkmcnt(0)" ::: "memory"); __builtin_amdgcn_sched_barrier(0); } while (0)

__device__ __forceinline__ float us2f(u16 u) {
    unsigned int x = ((unsigned int)u) << 16;
    return __uint_as_float(x);
}
__device__ __forceinline__ u16 f2us(float f) {
    unsigned int x = __float_as_uint(f);
    unsigned int lsb = (x >> 16) & 1u;
    x += 0x7fffu + lsb;
    return (u16)(x >> 16);
}
__device__ __forceinline__ bf16x8 cvt8(const float* p) {
    float4 f1 = *(const float4*)p;
    float4 f2 = *(const float4*)(p + 4);
    bf16x8 r;
    r[0] = (short)f2us(f1.x); r[1] = (short)f2us(f1.y);
    r[2] = (short)f2us(f1.z); r[3] = (short)f2us(f1.w);
    r[4] = (short)f2us(f2.x); r[5] = (short)f2us(f2.y);
    r[6] = (short)f2us(f2.z); r[7] = (short)f2us(f2.w);
    return r;
}

// flags[0] = 1 if float buffers are bf16, 0 if f32
// flags[1] = 1 if mask is int32, 0 if int8/bool
__global__ void detect_kernel(const u16* __restrict__ w,
                              const unsigned int* __restrict__ mask,
                              int* __restrict__ flags) {
    if (threadIdx.x == 0 && blockIdx.x == 0) {
        int plaus = 0;
        for (int i = 0; i < 256; i++) {
            u16 hw = w[i];
            int e = (hw >> 7) & 0xFF;
            if (e == 0 || (e >= 87 && e <= 131)) plaus++;
        }
        flags[0] = (plaus >= 205) ? 1 : 0;
        int ok = 1;
        for (int i = 0; i < 64; i++) if (mask[i] > 1u) ok = 0;
        flags[1] = ok;
    }
}

// Pack mask into bits: packed[(b*T + t)*16 + g], bit k = mask[b][t][k*16 + g].
__global__ __launch_bounds__(256) void pack_mask(const void* __restrict__ mask,
                                                 unsigned int* __restrict__ packed,
                                                 const int* __restrict__ flags) {
    const int idx = blockIdx.x * 256 + threadIdx.x;   // 8*512*16 = 65536 words
    const int g = idx & 15;
    const size_t bt = (size_t)(idx >> 4);
    unsigned int bits = 0;
    if (flags[1]) {
        const int* mp = (const int*)mask + bt * TT + g;
        #pragma unroll
        for (int k = 0; k < 32; k++) if (mp[k * 16] != 0) bits |= (1u << k);
    } else {
        const signed char* mp = (const signed char*)mask + bt * TT + g;
        #pragma unroll
        for (int k = 0; k < 32; k++) if (mp[k * 16] != 0) bits |= (1u << k);
    }
    packed[idx] = bits;
}

// ---------------- Unified MFMA GEMM: C[i,n] = sum_k A[i,k]*W[n,k] (+bias)
// (Round-7 measured structure: 64x64 tile, 4 MFMA/K-step.)
// OMODE 0: qkv scatter (q->f32 [bh][t][d], k->bf16 [bh][t][d], v->bf16 TRANSPOSED [bh][d][t])
// OMODE 1: pos scatter bf16 [h][s'][d], h-stride 1024 rows, guard i<M
// OMODE 2: A from ctx f32 (qT head-major), out [M,N] + bias (dtype per flag)
template<int OMODE>
__global__ __launch_bounds__(256) void gemm_mfma(
    const void* __restrict__ Av, const void* __restrict__ Wv,
    const void* __restrict__ bias, const int* __restrict__ flags,
    float* __restrict__ qT, u16* __restrict__ kB, u16* __restrict__ vB,
    u16* __restrict__ pB, void* __restrict__ oout, int M, int N, int K)
{
    const bool isbf = (flags[0] != 0);
    __shared__ u16 As[64][40];   // [m 0..63][k 0..31], +8 pad
    __shared__ u16 Bs[64][40];   // [n 0..63][k 0..31], +8 pad
    const int tid = threadIdx.x;
    const int w = tid >> 6, lane = tid & 63;
    const int quad = lane >> 4, l16 = lane & 15;
    const int bn = blockIdx.x * 64, bm = blockIdx.y * 64;
    const int srow = tid >> 2;          // 0..63 staging row
    const int koff = (tid & 3) * 8;     // 0,8,16,24
    const int garow = (OMODE == 1) ? min(bm + srow, M - 1) : (bm + srow);
    const int gbrow = bn + srow;

    f32x4 C[4];
    #pragma unroll
    for (int i = 0; i < 4; i++) { C[i][0] = 0.f; C[i][1] = 0.f; C[i][2] = 0.f; C[i][3] = 0.f; }

    for (int k0 = 0; k0 < K; k0 += 32) {
        bf16x8 av, bv;
        if (OMODE == 2) {
            const int kk = k0 + koff;
            const float* ap = qT + (((size_t)((garow >> 9) * HH + (kk >> 6)) * TT + (garow & 511)) << 6) + (kk & 63);
            av = cvt8(ap);
        } else if (isbf) {
            av = *(const bf16x8*)((const u16*)Av + (size_t)garow * K + k0 + koff);
        } else {
            av = cvt8((const float*)Av + (size_t)garow * K + k0 + koff);
        }
        if (isbf) {
            bv = *(const bf16x8*)((const u16*)Wv + (size_t)gbrow * K + k0 + koff);
        } else {
            bv = cvt8((const float*)Wv + (size_t)gbrow * K + k0 + koff);
        }

        __syncthreads();
        *(bf16x8*)&As[srow][koff] = av;
        *(bf16x8*)&Bs[srow][koff] = bv;
        __syncthreads();

        bf16x8 af = *(const bf16x8*)&As[w * 16 + l16][quad * 8];
        #pragma unroll
        for (int ct = 0; ct < 4; ct++) {
            bf16x8 bf = *(const bf16x8*)&Bs[ct * 16 + l16][quad * 8];
            C[ct] = MFMA16(af, bf, C[ct]);
        }
    }

    #pragma unroll
    for (int ct = 0; ct < 4; ct++) {
        #pragma unroll
        for (int r = 0; r < 4; r++) {
            const int i = bm + w * 16 + quad * 4 + r;
            const int n = bn + ct * 16 + l16;
            float val = C[ct][r];
            if (OMODE == 0) {
                val += isbf ? us2f(((const u16*)bias)[n]) : ((const float*)bias)[n];
                const int sec = n >> 10, w_ = n & 1023;
                const int h_ = w_ >> 6, d_ = w_ & 63;
                const size_t bh_ = (size_t)((i >> 9) * HH + h_);
                const int t_ = i & 511;
                if (sec == 0) qT[((bh_ * TT + t_) << 6) + d_] = val;
                else if (sec == 1) kB[((bh_ * TT + t_) << 6) + d_] = f2us(val);
                else vB[((bh_ * DKK + d_) << 9) + t_] = f2us(val);
            } else if (OMODE == 1) {
                if (i < M) {
                    const int h_ = n >> 6, d_ = n & 63;
                    pB[((size_t)(h_ * 1024 + i) << 6) + d_] = f2us(val);
                }
            } else {
                val += isbf ? us2f(((const u16*)bias)[n]) : ((const float*)bias)[n];
                if (isbf) ((u16*)oout)[(size_t)i * N + n] = f2us(val);
                else ((float*)oout)[(size_t)i * N + n] = val;
            }
        }
    }
}

// ---------------- MFMA attention: grid = (b, h, t-tile) -- b on blockIdx.x.
// x is the fastest dispatch dimension, so bid % 8 == b: every block of batch b
// lands on XCD b (round-robin), and that XCD's 4 MB L2 holds b's K+V (2 MB)
// plus P (2 MB) instead of all 8 XCDs re-fetching copies (the 92.6 MB FETCH).
// Same swizzle property as the 1D mapping, zero new index arithmetic.
// All LDS is per-wave -> NO block barriers anywhere (wave-local lgkmcnt only).
__global__ __launch_bounds__(256) void attn_mfma(
    float* __restrict__ qT, const u16* __restrict__ kB, const u16* __restrict__ vB,
    const u16* __restrict__ pB, const void* __restrict__ posu,
    const void* __restrict__ posv, const unsigned int* __restrict__ pmask,
    void* __restrict__ d_out, const int* __restrict__ flags)
{
    const int b = blockIdx.x;
    const int h = blockIdx.y;
    const int t0 = blockIdx.z << 6;
    const int tid = threadIdx.x;
    const int w = tid >> 6, lane = tid & 63;
    const int quad = lane >> 4, l16 = lane & 15;
    const bool isbf = (flags[0] != 0);
    const size_t bh = (size_t)b * HH + h;

    __shared__ u16 wls[4][16][520];          // per-wave weights tile (also aliased as bd f32)
    u16* wme = &wls[w][0][0];
    float* bdw = (float*)wme;                // [16][84] f32 scratch, per-wave

    // ---- packed mask words (4 coalesced u32 loads/thread, hoisted early)
    const int trow = t0 + w * 16 + quad * 4;
    unsigned int mrow[4];
    #pragma unroll
    for (int r = 0; r < 4; r++)
        mrow[r] = pmask[((size_t)(b * TT + trow + r) << 4) + l16];

    // ---- A fragments q_u, q_v (prescaled by 0.125 so scores come out /8)
    const int myrow = t0 + w * 16 + l16;
    const float* qrow = qT + ((bh * TT + myrow) << 6);
    bf16x8 aU[2], aV[2];
    #pragma unroll
    for (int f = 0; f < 2; f++) {
        const int d0 = f * 32 + quad * 8;
        float q8[8], pu8[8], pv8[8];
        *(float4*)&q8[0] = *(const float4*)(qrow + d0);
        *(float4*)&q8[4] = *(const float4*)(qrow + d0 + 4);
        if (isbf) {
            const u16* puP = (const u16*)posu + h * 64 + d0;
            const u16* pvP = (const u16*)posv + h * 64 + d0;
            #pragma unroll
            for (int j = 0; j < 8; j++) { pu8[j] = us2f(puP[j]); pv8[j] = us2f(pvP[j]); }
        } else {
            const float* puP = (const float*)posu + h * 64 + d0;
            const float* pvP = (const float*)posv + h * 64 + d0;
            #pragma unroll
            for (int j = 0; j < 8; j++) { pu8[j] = puP[j]; pv8[j] = pvP[j]; }
        }
        #pragma unroll
        for (int j = 0; j < 8; j++) {
            aU[f][j] = (short)f2us((q8[j] + pu8[j]) * 0.125f);
            aV[f][j] = (short)f2us((q8[j] + pv8[j]) * 0.125f);
        }
    }

    // ---- AC scores: S[32] covers 512 cols (s)
    f32x4 S[32];
    #pragma unroll
    for (int ct = 0; ct < 32; ct++) { S[ct][0] = 0.f; S[ct][1] = 0.f; S[ct][2] = 0.f; S[ct][3] = 0.f; }
    const u16* kbase = kB + ((bh * TT) << 6) + quad * 8;
    #pragma unroll
    for (int ct = 0; ct < 32; ct++) {
        const u16* kp = kbase + ((size_t)(ct * 16 + l16) << 6);
        bf16x8 b0 = *(const bf16x8*)kp;
        bf16x8 b1 = *(const bf16x8*)(kp + 32);
        S[ct] = MFMA16(aU[0], b0, S[ct]);
        S[ct] = MFMA16(aU[1], b1, S[ct]);
    }

    // ---- BD: 8 chunks of 64 cols; per-wave 16x80 tile via LDS, skewed gather
    const u16* pbaseh = pB + ((size_t)h << 16);  // h stride = 1024 rows * 64
    for (int g = 0; g < 8; g++) {
        const int pb = g * 64 - t0 + 496 - w * 16;  // P row for c_local=0 (>=0, <=944)
        #pragma unroll
        for (int c5 = 0; c5 < 5; c5++) {
            const u16* pp = pbaseh + ((size_t)(pb + c5 * 16 + l16) << 6) + quad * 8;
            bf16x8 b0 = *(const bf16x8*)pp;
            bf16x8 b1 = *(const bf16x8*)(pp + 32);
            f32x4 c; c[0] = 0.f; c[1] = 0.f; c[2] = 0.f; c[3] = 0.f;
            c = MFMA16(aV[0], b0, c);
            c = MFMA16(aV[1], b1, c);
            #pragma unroll
            for (int r = 0; r < 4; r++)
                bdw[(quad * 4 + r) * 84 + c5 * 16 + l16] = c[r];
        }
        WAVE_SYNC();   // per-wave write->read visibility; WAR handled by in-order DS
        #pragma unroll
        for (int f = 0; f < 4; f++) {
            const int sc = f * 16 + l16;
            #pragma unroll
            for (int r = 0; r < 4; r++) {
                const int local = quad * 4 + r;
                // bd[local][sc + 15 - local]
                S[g * 4 + f][r] += bdw[local * 83 + sc + 15];
            }
        }
    }

    // ---- mask (bit test, no memory traffic)
    #pragma unroll
    for (int ct = 0; ct < 32; ct++) {
        #pragma unroll
        for (int r = 0; r < 4; r++) {
            if (!(mrow[r] & (1u << ct))) S[ct][r] = -100000.0f;
        }
    }

    // ---- softmax (rows live across 16 lanes of this quad)
    float mx[4] = {-3.0e38f, -3.0e38f, -3.0e38f, -3.0e38f};
    float sm[4] = {0.f, 0.f, 0.f, 0.f};
    #pragma unroll
    for (int ct = 0; ct < 32; ct++)
        #pragma unroll
        for (int r = 0; r < 4; r++) mx[r] = fmaxf(mx[r], S[ct][r]);
    #pragma unroll
    for (int r = 0; r < 4; r++)
        #pragma unroll
        for (int off = 1; off < 16; off <<= 1) mx[r] = fmaxf(mx[r], __shfl_xor(mx[r], off, 64));
    #pragma unroll
    for (int ct = 0; ct < 32; ct++)
        #pragma unroll
        for (int r = 0; r < 4; r++) {
            float e = __expf(S[ct][r] - mx[r]);
            S[ct][r] = e;
            sm[r] += e;
        }
    #pragma unroll
    for (int r = 0; r < 4; r++) {
        #pragma unroll
        for (int off = 1; off < 16; off <<= 1) sm[r] += __shfl_xor(sm[r], off, 64);
        sm[r] = 1.0f / sm[r];
    }

    // ---- weights: stage per-wave LDS tile (A-operand layout), then
    //      coalesced global store from LDS (bf16 path: 16 x 1KB/wave dwordx4)
    const size_t wbase = (size_t)BB * TT * DD + (((bh * TT + trow)) << 9) + l16;
    #pragma unroll
    for (int ct = 0; ct < 32; ct++) {
        #pragma unroll
        for (int r = 0; r < 4; r++) {
            const float wv = S[ct][r] * sm[r];
            wls[w][quad * 4 + r][ct * 16 + l16] = f2us(wv);
            if (!isbf) ((float*)d_out)[wbase + ((size_t)r << 9) + ct * 16] = wv;
        }
    }
    WAVE_SYNC();
    if (isbf) {
        u16* wout = (u16*)d_out + (size_t)BB * TT * DD + ((bh * TT + t0 + w * 16) << 9);
        const int lane8 = lane * 8;
        #pragma unroll
        for (int rr = 0; rr < 16; rr++) {
            bf16x8 vv = *(const bf16x8*)&wls[w][rr][lane8];
            *(bf16x8*)(wout + ((size_t)rr << 9) + lane8) = vv;
        }
    }

    // ---- PV: ctx[16x64] = W[16x512] x V[512x64], V transposed [bh][d][s]
    f32x4 Cv[4];
    #pragma unroll
    for (int i = 0; i < 4; i++) { Cv[i][0] = 0.f; Cv[i][1] = 0.f; Cv[i][2] = 0.f; Cv[i][3] = 0.f; }
    const u16* vb0 = vB + ((bh * DKK) << 9) + quad * 8;
    #pragma unroll
    for (int ks = 0; ks < 16; ks++) {
        bf16x8 aw = *(const bf16x8*)&wls[w][l16][ks * 32 + quad * 8];
        #pragma unroll
        for (int ctd = 0; ctd < 4; ctd++) {
            const u16* vp = vb0 + ((size_t)(ctd * 16 + l16) << 9) + ks * 32;
            bf16x8 bv = *(const bf16x8*)vp;
            Cv[ctd] = MFMA16(aw, bv, Cv[ctd]);
        }
    }
    // ctx overwrites this block's own q rows (read-complete)
    float* crow = qT + ((bh * TT + trow) << 6) + l16;
    #pragma unroll
    for (int ctd = 0; ctd < 4; ctd++)
        #pragma unroll
        for (int r = 0; r < 4; r++)
            crow[(r << 6) + ctd * 16] = Cv[ctd][r];
}

extern "C" void kernel_launch(void* const* d_in, const int* in_sizes, int n_in,
                              void* d_out, int out_size, void* d_ws, size_t ws_size,
                              hipStream_t stream)
{
    const void* x    = d_in[0];
    const void* mask = d_in[1];
    const void* pos  = d_in[2];
    const void* Wqkv = d_in[3];
    const void* bqkv = d_in[4];
    const void* Wpos = d_in[5];
    const void* posu = d_in[6];
    const void* posv = d_in[7];
    const void* Wout = d_in[8];
    const void* bout = d_in[9];

    char* ws = (char*)d_ws;
    float* qT    = (float*)(ws + 0);                 // [B,H,T,64] f32 16 MiB (ctx reuses)
    u16*   kB    = (u16*)(ws + 16777216);            // [B,H,T,64] bf16 8 MiB
    u16*   vB    = (u16*)(ws + 25165824);            // [B,H,64,T] bf16 8 MiB (transposed)
    u16*   pB    = (u16*)(ws + 33554432);            // [H,1024,64] bf16 2 MiB (row 1023 = pad)
    int*   flags = (int*)(ws + 35651584);
    unsigned int* pmask = (unsigned int*)(ws + 35655680);  // [B,T,16] u32, 256 KiB

    detect_kernel<<<1, 64, 0, stream>>>((const u16*)Wqkv, (const unsigned int*)mask, flags);
    pack_mask<<<dim3(256), 256, 0, stream>>>(mask, pmask, flags);

    // 1) qkv = x @ Wqkv^T + bqkv -> q(f32), k(bf16), v(bf16 transposed)
    gemm_mfma<0><<<dim3(48, 64), 256, 0, stream>>>(
        x, Wqkv, bqkv, flags, qT, kB, vB, pB, nullptr, BB * TT, 3 * DD, DD);

    // 2) p = pos @ Wpos^T -> bf16 [H,1024,64]
    gemm_mfma<1><<<dim3(16, 16), 256, 0, stream>>>(
        pos, Wpos, nullptr, flags, qT, kB, vB, pB, nullptr, SS, DD, DD);

    // 3) attention (b on x => XCD-pinned batches): weights -> d_out, ctx -> qT
    attn_mfma<<<dim3(BB, HH, 8), 256, 0, stream>>>(
        qT, kB, vB, pB, posu, posv, pmask, d_out, flags);

    // 4) out = ctx @ Wout^T + bout
    gemm_mfma<2><<<dim3(16, 64), 256, 0, stream>>>(
        nullptr, Wout, bout, flags, qT, kB, vB, pB, d_out, BB * TT, DD, DD);
}

// Round 14
// 496.017 us; speedup vs baseline: 1.0353x; 1.0049x over previous
//
#include <hip/hip_runtime.h>

#define BB 8
#define TT 512
#define DD 1024
#define HH 16
#define DKK 64
#define SS 1023

typedef unsigned short u16;
typedef __attribute__((ext_vector_type(8))) short bf16x8;
typedef __attribute__((ext_vector_type(4))) float f32x4;

#define MFMA16(a, b, c) __builtin_amdgcn_mfma_f32_16x16x32_bf16((a), (b), (c), 0, 0, 0)

// Wave-local LDS fence: all LDS traffic in attn_mfma is per-wave (wls[w]),
// so a block barrier is never needed -- just drain this wave's DS queue and
// pin the schedule (guide rule #18).
#define WAVE_SYNC() do { asm volatile("s_waitcnt lgkmcnt(0)" ::: "memory"); __builtin_amdgcn_sched_barrier(0); } while (0)

__device__ __forceinline__ float us2f(u16 u) {
    unsigned int x = ((unsigned int)u) << 16;
    return __uint_as_float(x);
}
__device__ __forceinline__ u16 f2us(float f) {
    unsigned int x = __float_as_uint(f);
    unsigned int lsb = (x >> 16) & 1u;
    x += 0x7fffu + lsb;
    return (u16)(x >> 16);
}
__device__ __forceinline__ bf16x8 cvt8(const float* p) {
    float4 f1 = *(const float4*)p;
    float4 f2 = *(const float4*)(p + 4);
    bf16x8 r;
    r[0] = (short)f2us(f1.x); r[1] = (short)f2us(f1.y);
    r[2] = (short)f2us(f1.z); r[3] = (short)f2us(f1.w);
    r[4] = (short)f2us(f2.x); r[5] = (short)f2us(f2.y);
    r[6] = (short)f2us(f2.z); r[7] = (short)f2us(f2.w);
    return r;
}

// flags[0] = 1 if float buffers are bf16, 0 if f32
// flags[1] = 1 if mask is int32, 0 if int8/bool
__global__ void detect_kernel(const u16* __restrict__ w,
                              const unsigned int* __restrict__ mask,
                              int* __restrict__ flags) {
    if (threadIdx.x == 0 && blockIdx.x == 0) {
        int plaus = 0;
        for (int i = 0; i < 256; i++) {
            u16 hw = w[i];
            int e = (hw >> 7) & 0xFF;
            if (e == 0 || (e >= 87 && e <= 131)) plaus++;
        }
        flags[0] = (plaus >= 205) ? 1 : 0;
        int ok = 1;
        for (int i = 0; i < 64; i++) if (mask[i] > 1u) ok = 0;
        flags[1] = ok;
    }
}

// Pack mask into bits: packed[(b*T + t)*16 + g], bit k = mask[b][t][k*16 + g].
__global__ __launch_bounds__(256) void pack_mask(const void* __restrict__ mask,
                                                 unsigned int* __restrict__ packed,
                                                 const int* __restrict__ flags) {
    const int idx = blockIdx.x * 256 + threadIdx.x;   // 8*512*16 = 65536 words
    const int g = idx & 15;
    const size_t bt = (size_t)(idx >> 4);
    unsigned int bits = 0;
    if (flags[1]) {
        const int* mp = (const int*)mask + bt * TT + g;
        #pragma unroll
        for (int k = 0; k < 32; k++) if (mp[k * 16] != 0) bits |= (1u << k);
    } else {
        const signed char* mp = (const signed char*)mask + bt * TT + g;
        #pragma unroll
        for (int k = 0; k < 32; k++) if (mp[k * 16] != 0) bits |= (1u << k);
    }
    packed[idx] = bits;
}

// ---------------- Unified MFMA GEMM: C[i,n] = sum_k A[i,k]*W[n,k] (+bias)
// (Round-7 measured structure: 64x64 tile, 4 MFMA/K-step.)
// OMODE 0: qkv scatter (q->f32 [bh][t][d], k->bf16 [bh][t][d], v->bf16 TRANSPOSED [bh][d][t])
// OMODE 1: pos scatter bf16 [h][s'][d], h-stride 1024 rows, guard i<M
// OMODE 2: A from ctx f32 (qT head-major), out [M,N] + bias (dtype per flag)
template<int OMODE>
__global__ __launch_bounds__(256) void gemm_mfma(
    const void* __restrict__ Av, const void* __restrict__ Wv,
    const void* __restrict__ bias, const int* __restrict__ flags,
    float* __restrict__ qT, u16* __restrict__ kB, u16* __restrict__ vB,
    u16* __restrict__ pB, void* __restrict__ oout, int M, int N, int K)
{
    const bool isbf = (flags[0] != 0);
    __shared__ u16 As[64][40];   // [m 0..63][k 0..31], +8 pad
    __shared__ u16 Bs[64][40];   // [n 0..63][k 0..31], +8 pad
    const int tid = threadIdx.x;
    const int w = tid >> 6, lane = tid & 63;
    const int quad = lane >> 4, l16 = lane & 15;
    const int bn = blockIdx.x * 64, bm = blockIdx.y * 64;
    const int srow = tid >> 2;          // 0..63 staging row
    const int koff = (tid & 3) * 8;     // 0,8,16,24
    const int garow = (OMODE == 1) ? min(bm + srow, M - 1) : (bm + srow);
    const int gbrow = bn + srow;

    f32x4 C[4];
    #pragma unroll
    for (int i = 0; i < 4; i++) { C[i][0] = 0.f; C[i][1] = 0.f; C[i][2] = 0.f; C[i][3] = 0.f; }

    for (int k0 = 0; k0 < K; k0 += 32) {
        bf16x8 av, bv;
        if (OMODE == 2) {
            const int kk = k0 + koff;
            const float* ap = qT + (((size_t)((garow >> 9) * HH + (kk >> 6)) * TT + (garow & 511)) << 6) + (kk & 63);
            av = cvt8(ap);
        } else if (isbf) {
            av = *(const bf16x8*)((const u16*)Av + (size_t)garow * K + k0 + koff);
        } else {
            av = cvt8((const float*)Av + (size_t)garow * K + k0 + koff);
        }
        if (isbf) {
            bv = *(const bf16x8*)((const u16*)Wv + (size_t)gbrow * K + k0 + koff);
        } else {
            bv = cvt8((const float*)Wv + (size_t)gbrow * K + k0 + koff);
        }

        __syncthreads();
        *(bf16x8*)&As[srow][koff] = av;
        *(bf16x8*)&Bs[srow][koff] = bv;
        __syncthreads();

        bf16x8 af = *(const bf16x8*)&As[w * 16 + l16][quad * 8];
        #pragma unroll
        for (int ct = 0; ct < 4; ct++) {
            bf16x8 bf = *(const bf16x8*)&Bs[ct * 16 + l16][quad * 8];
            C[ct] = MFMA16(af, bf, C[ct]);
        }
    }

    #pragma unroll
    for (int ct = 0; ct < 4; ct++) {
        #pragma unroll
        for (int r = 0; r < 4; r++) {
            const int i = bm + w * 16 + quad * 4 + r;
            const int n = bn + ct * 16 + l16;
            float val = C[ct][r];
            if (OMODE == 0) {
                val += isbf ? us2f(((const u16*)bias)[n]) : ((const float*)bias)[n];
                const int sec = n >> 10, w_ = n & 1023;
                const int h_ = w_ >> 6, d_ = w_ & 63;
                const size_t bh_ = (size_t)((i >> 9) * HH + h_);
                const int t_ = i & 511;
                if (sec == 0) qT[((bh_ * TT + t_) << 6) + d_] = val;
                else if (sec == 1) kB[((bh_ * TT + t_) << 6) + d_] = f2us(val);
                else vB[((bh_ * DKK + d_) << 9) + t_] = f2us(val);
            } else if (OMODE == 1) {
                if (i < M) {
                    const int h_ = n >> 6, d_ = n & 63;
                    pB[((size_t)(h_ * 1024 + i) << 6) + d_] = f2us(val);
                }
            } else {
                val += isbf ? us2f(((const u16*)bias)[n]) : ((const float*)bias)[n];
                if (isbf) ((u16*)oout)[(size_t)i * N + n] = f2us(val);
                else ((float*)oout)[(size_t)i * N + n] = val;
            }
        }
    }
}

// ---------------- MFMA attention: grid = (b, h, t-tile), b on blockIdx.x
// (XCD-pinned batches: FETCH 92.6 -> 61.9 MB measured, r12).
// LDS shrunk to [4][16][268] u16 = 34.3 KB (was 66.5 KB) by splitting PV into
// two 256-col passes -> 3 blocks/CU residency (was ~1-2), the occupancy lever.
// All LDS is per-wave -> NO block barriers (wave-local lgkmcnt only).
__global__ __launch_bounds__(256) void attn_mfma(
    float* __restrict__ qT, const u16* __restrict__ kB, const u16* __restrict__ vB,
    const u16* __restrict__ pB, const void* __restrict__ posu,
    const void* __restrict__ posv, const unsigned int* __restrict__ pmask,
    void* __restrict__ d_out, const int* __restrict__ flags)
{
    const int b = blockIdx.x;
    const int h = blockIdx.y;
    const int t0 = blockIdx.z << 6;
    const int tid = threadIdx.x;
    const int w = tid >> 6, lane = tid & 63;
    const int quad = lane >> 4, l16 = lane & 15;
    const bool isbf = (flags[0] != 0);
    const size_t bh = (size_t)b * HH + h;

    __shared__ u16 wls[4][16][268];          // per-wave tile: bd f32 scratch / half-weights
    u16* wme = &wls[w][0][0];
    float* bdw = (float*)wme;                // [16][84] f32 scratch, per-wave (skewed)

    // ---- packed mask words (4 coalesced u32 loads/thread, hoisted early)
    const int trow = t0 + w * 16 + quad * 4;
    unsigned int mrow[4];
    #pragma unroll
    for (int r = 0; r < 4; r++)
        mrow[r] = pmask[((size_t)(b * TT + trow + r) << 4) + l16];

    // ---- A fragments q_u, q_v (prescaled by 0.125 so scores come out /8)
    const int myrow = t0 + w * 16 + l16;
    const float* qrow = qT + ((bh * TT + myrow) << 6);
    bf16x8 aU[2], aV[2];
    #pragma unroll
    for (int f = 0; f < 2; f++) {
        const int d0 = f * 32 + quad * 8;
        float q8[8], pu8[8], pv8[8];
        *(float4*)&q8[0] = *(const float4*)(qrow + d0);
        *(float4*)&q8[4] = *(const float4*)(qrow + d0 + 4);
        if (isbf) {
            const u16* puP = (const u16*)posu + h * 64 + d0;
            const u16* pvP = (const u16*)posv + h * 64 + d0;
            #pragma unroll
            for (int j = 0; j < 8; j++) { pu8[j] = us2f(puP[j]); pv8[j] = us2f(pvP[j]); }
        } else {
            const float* puP = (const float*)posu + h * 64 + d0;
            const float* pvP = (const float*)posv + h * 64 + d0;
            #pragma unroll
            for (int j = 0; j < 8; j++) { pu8[j] = puP[j]; pv8[j] = pvP[j]; }
        }
        #pragma unroll
        for (int j = 0; j < 8; j++) {
            aU[f][j] = (short)f2us((q8[j] + pu8[j]) * 0.125f);
            aV[f][j] = (short)f2us((q8[j] + pv8[j]) * 0.125f);
        }
    }

    // ---- AC scores: S[32] covers 512 cols (s)
    f32x4 S[32];
    #pragma unroll
    for (int ct = 0; ct < 32; ct++) { S[ct][0] = 0.f; S[ct][1] = 0.f; S[ct][2] = 0.f; S[ct][3] = 0.f; }
    const u16* kbase = kB + ((bh * TT) << 6) + quad * 8;
    #pragma unroll
    for (int ct = 0; ct < 32; ct++) {
        const u16* kp = kbase + ((size_t)(ct * 16 + l16) << 6);
        bf16x8 b0 = *(const bf16x8*)kp;
        bf16x8 b1 = *(const bf16x8*)(kp + 32);
        S[ct] = MFMA16(aU[0], b0, S[ct]);
        S[ct] = MFMA16(aU[1], b1, S[ct]);
    }

    // ---- BD: 8 chunks of 64 cols; per-wave 16x80 tile via LDS, skewed gather
    const u16* pbaseh = pB + ((size_t)h << 16);  // h stride = 1024 rows * 64
    for (int g = 0; g < 8; g++) {
        const int pb = g * 64 - t0 + 496 - w * 16;  // P row for c_local=0 (>=0, <=944)
        #pragma unroll
        for (int c5 = 0; c5 < 5; c5++) {
            const u16* pp = pbaseh + ((size_t)(pb + c5 * 16 + l16) << 6) + quad * 8;
            bf16x8 b0 = *(const bf16x8*)pp;
            bf16x8 b1 = *(const bf16x8*)(pp + 32);
            f32x4 c; c[0] = 0.f; c[1] = 0.f; c[2] = 0.f; c[3] = 0.f;
            c = MFMA16(aV[0], b0, c);
            c = MFMA16(aV[1], b1, c);
            #pragma unroll
            for (int r = 0; r < 4; r++)
                bdw[(quad * 4 + r) * 84 + c5 * 16 + l16] = c[r];
        }
        WAVE_SYNC();   // per-wave write->read visibility; WAR handled by in-order DS
        #pragma unroll
        for (int f = 0; f < 4; f++) {
            const int sc = f * 16 + l16;
            #pragma unroll
            for (int r = 0; r < 4; r++) {
                const int local = quad * 4 + r;
                // bd[local][sc + 15 - local]
                S[g * 4 + f][r] += bdw[local * 83 + sc + 15];
            }
        }
    }

    // ---- mask (bit test, no memory traffic)
    #pragma unroll
    for (int ct = 0; ct < 32; ct++) {
        #pragma unroll
        for (int r = 0; r < 4; r++) {
            if (!(mrow[r] & (1u << ct))) S[ct][r] = -100000.0f;
        }
    }

    // ---- softmax (rows live across 16 lanes of this quad)
    float mx[4] = {-3.0e38f, -3.0e38f, -3.0e38f, -3.0e38f};
    float sm[4] = {0.f, 0.f, 0.f, 0.f};
    #pragma unroll
    for (int ct = 0; ct < 32; ct++)
        #pragma unroll
        for (int r = 0; r < 4; r++) mx[r] = fmaxf(mx[r], S[ct][r]);
    #pragma unroll
    for (int r = 0; r < 4; r++)
        #pragma unroll
        for (int off = 1; off < 16; off <<= 1) mx[r] = fmaxf(mx[r], __shfl_xor(mx[r], off, 64));
    #pragma unroll
    for (int ct = 0; ct < 32; ct++)
        #pragma unroll
        for (int r = 0; r < 4; r++) {
            float e = __expf(S[ct][r] - mx[r]);
            S[ct][r] = e;
            sm[r] += e;
        }
    #pragma unroll
    for (int r = 0; r < 4; r++) {
        #pragma unroll
        for (int off = 1; off < 16; off <<= 1) sm[r] += __shfl_xor(sm[r], off, 64);
        sm[r] = 1.0f / sm[r];
    }

    // ---- weights + PV in TWO 256-col passes (halves LDS -> 3 blocks/CU).
    // Same accumulation order as single-pass (ks ascending), bit-identical.
    f32x4 Cv[4];
    #pragma unroll
    for (int i = 0; i < 4; i++) { Cv[i][0] = 0.f; Cv[i][1] = 0.f; Cv[i][2] = 0.f; Cv[i][3] = 0.f; }
    const u16* vb0 = vB + ((bh * DKK) << 9) + quad * 8;
    const size_t wbase = (size_t)BB * TT * DD + (((bh * TT + trow)) << 9) + l16;

    #pragma unroll
    for (int p = 0; p < 2; p++) {
        // stage weights cols [p*256, p*256+256) into per-wave LDS + global store
        #pragma unroll
        for (int cl = 0; cl < 16; cl++) {
            const int ct = p * 16 + cl;
            #pragma unroll
            for (int r = 0; r < 4; r++) {
                const float wv = S[ct][r] * sm[r];
                wls[w][quad * 4 + r][cl * 16 + l16] = f2us(wv);
                if (!isbf) ((float*)d_out)[wbase + ((size_t)r << 9) + ct * 16] = wv;
            }
        }
        WAVE_SYNC();
        if (isbf) {
            // coalesced bf16 store from LDS: 8 insts x 2 rows x 256 cols
            u16* wout = (u16*)d_out + (size_t)BB * TT * DD + ((bh * TT + t0 + w * 16) << 9) + p * 256;
            const int sr = lane >> 5, sc8 = (lane & 31) * 8;
            #pragma unroll
            for (int rr = 0; rr < 8; rr++) {
                bf16x8 vv = *(const bf16x8*)&wls[w][rr * 2 + sr][sc8];
                *(bf16x8*)(wout + ((size_t)(rr * 2 + sr) << 9) + sc8) = vv;
            }
        }
        // PV over this half's ks range (WAR on next pass's writes: in-order DS)
        #pragma unroll
        for (int kl = 0; kl < 8; kl++) {
            const int ks = p * 8 + kl;
            bf16x8 aw = *(const bf16x8*)&wls[w][l16][kl * 32 + quad * 8];
            #pragma unroll
            for (int ctd = 0; ctd < 4; ctd++) {
                const u16* vp = vb0 + ((size_t)(ctd * 16 + l16) << 9) + ks * 32;
                bf16x8 bv = *(const bf16x8*)vp;
                Cv[ctd] = MFMA16(aw, bv, Cv[ctd]);
            }
        }
        WAVE_SYNC();   // drain PV reads before next pass overwrites (order pin)
    }

    // ctx overwrites this block's own q rows (read-complete)
    float* crow = qT + ((bh * TT + trow) << 6) + l16;
    #pragma unroll
    for (int ctd = 0; ctd < 4; ctd++)
        #pragma unroll
        for (int r = 0; r < 4; r++)
            crow[(r << 6) + ctd * 16] = Cv[ctd][r];
}

extern "C" void kernel_launch(void* const* d_in, const int* in_sizes, int n_in,
                              void* d_out, int out_size, void* d_ws, size_t ws_size,
                              hipStream_t stream)
{
    const void* x    = d_in[0];
    const void* mask = d_in[1];
    const void* pos  = d_in[2];
    const void* Wqkv = d_in[3];
    const void* bqkv = d_in[4];
    const void* Wpos = d_in[5];
    const void* posu = d_in[6];
    const void* posv = d_in[7];
    const void* Wout = d_in[8];
    const void* bout = d_in[9];

    char* ws = (char*)d_ws;
    float* qT    = (float*)(ws + 0);                 // [B,H,T,64] f32 16 MiB (ctx reuses)
    u16*   kB    = (u16*)(ws + 16777216);            // [B,H,T,64] bf16 8 MiB
    u16*   vB    = (u16*)(ws + 25165824);            // [B,H,64,T] bf16 8 MiB (transposed)
    u16*   pB    = (u16*)(ws + 33554432);            // [H,1024,64] bf16 2 MiB (row 1023 = pad)
    int*   flags = (int*)(ws + 35651584);
    unsigned int* pmask = (unsigned int*)(ws + 35655680);  // [B,T,16] u32, 256 KiB

    detect_kernel<<<1, 64, 0, stream>>>((const u16*)Wqkv, (const unsigned int*)mask, flags);
    pack_mask<<<dim3(256), 256, 0, stream>>>(mask, pmask, flags);

    // 1) qkv = x @ Wqkv^T + bqkv -> q(f32), k(bf16), v(bf16 transposed)
    gemm_mfma<0><<<dim3(48, 64), 256, 0, stream>>>(
        x, Wqkv, bqkv, flags, qT, kB, vB, pB, nullptr, BB * TT, 3 * DD, DD);

    // 2) p = pos @ Wpos^T -> bf16 [H,1024,64]
    gemm_mfma<1><<<dim3(16, 16), 256, 0, stream>>>(
        pos, Wpos, nullptr, flags, qT, kB, vB, pB, nullptr, SS, DD, DD);

    // 3) attention (b on x => XCD-pinned batches): weights -> d_out, ctx -> qT
    attn_mfma<<<dim3(BB, HH, 8), 256, 0, stream>>>(
        qT, kB, vB, pB, posu, posv, pmask, d_out, flags);

    // 4) out = ctx @ Wout^T + bout
    gemm_mfma<2><<<dim3(16, 64), 256, 0, stream>>>(
        nullptr, Wout, bout, flags, qT, kB, vB, pB, d_out, BB * TT, DD, DD);
}

// Round 17
// 442.664 us; speedup vs baseline: 1.1601x; 1.1205x over previous
//
#include <hip/hip_runtime.h>

#define BB 8
#define TT 512
#define DD 1024
#define HH 16
#define DKK 64
#define SS 1023

typedef unsigned short u16;
typedef __attribute__((ext_vector_type(8))) short bf16x8;
typedef __attribute__((ext_vector_type(4))) float f32x4;

#define MFMA16(a, b, c) __builtin_amdgcn_mfma_f32_16x16x32_bf16((a), (b), (c), 0, 0, 0)

// Wave-local LDS fence (attn only; all attn LDS is per-wave)
#define WAVE_SYNC() do { asm volatile("s_waitcnt lgkmcnt(0)" ::: "memory"); __builtin_amdgcn_sched_barrier(0); } while (0)

__device__ __forceinline__ float us2f(u16 u) {
    unsigned int x = ((unsigned int)u) << 16;
    return __uint_as_float(x);
}
__device__ __forceinline__ u16 f2us(float f) {
    unsigned int x = __float_as_uint(f);
    unsigned int lsb = (x >> 16) & 1u;
    x += 0x7fffu + lsb;
    return (u16)(x >> 16);
}
__device__ __forceinline__ bf16x8 cvt8(const float* p) {
    float4 f1 = *(const float4*)p;
    float4 f2 = *(const float4*)(p + 4);
    bf16x8 r;
    r[0] = (short)f2us(f1.x); r[1] = (short)f2us(f1.y);
    r[2] = (short)f2us(f1.z); r[3] = (short)f2us(f1.w);
    r[4] = (short)f2us(f2.x); r[5] = (short)f2us(f2.y);
    r[6] = (short)f2us(f2.z); r[7] = (short)f2us(f2.w);
    return r;
}
__device__ __forceinline__ void gload_lds16(const u16* g, u16* l) {
    __builtin_amdgcn_global_load_lds(
        (const __attribute__((address_space(1))) void*)g,
        (__attribute__((address_space(3))) void*)l, 16, 0, 0);
}

// flags[0] = 1 if float buffers are bf16, 0 if f32
// flags[1] = 1 if mask is int32, 0 if int8/bool
__global__ void detect_kernel(const u16* __restrict__ w,
                              const unsigned int* __restrict__ mask,
                              int* __restrict__ flags) {
    if (threadIdx.x == 0 && blockIdx.x == 0) {
        int plaus = 0;
        for (int i = 0; i < 256; i++) {
            u16 hw = w[i];
            int e = (hw >> 7) & 0xFF;
            if (e == 0 || (e >= 87 && e <= 131)) plaus++;
        }
        flags[0] = (plaus >= 205) ? 1 : 0;
        int ok = 1;
        for (int i = 0; i < 64; i++) if (mask[i] > 1u) ok = 0;
        flags[1] = ok;
    }
}

// Pack mask into bits: packed[(b*T + t)*16 + g], bit k = mask[b][t][k*16 + g].
__global__ __launch_bounds__(256) void pack_mask(const void* __restrict__ mask,
                                                 unsigned int* __restrict__ packed,
                                                 const int* __restrict__ flags) {
    const int idx = blockIdx.x * 256 + threadIdx.x;   // 8*512*16 = 65536 words
    const int g = idx & 15;
    const size_t bt = (size_t)(idx >> 4);
    unsigned int bits = 0;
    if (flags[1]) {
        const int* mp = (const int*)mask + bt * TT + g;
        #pragma unroll
        for (int k = 0; k < 32; k++) if (mp[k * 16] != 0) bits |= (1u << k);
    } else {
        const signed char* mp = (const signed char*)mask + bt * TT + g;
        #pragma unroll
        for (int k = 0; k < 32; k++) if (mp[k * 16] != 0) bits |= (1u << k);
    }
    packed[idx] = bits;
}

// Convert f32 -> bf16 (or copy bf16 when inputs are already bf16).
__global__ __launch_bounds__(256) void cvt_bf16(const void* __restrict__ src,
                                                u16* __restrict__ dst, int n8,
                                                const int* __restrict__ flags) {
    const bool isbf = (flags[0] != 0);
    int i = blockIdx.x * 256 + threadIdx.x;
    const int stride = gridDim.x * 256;
    for (; i < n8; i += stride) {
        if (isbf)
            *(bf16x8*)(dst + (size_t)i * 8) = *(const bf16x8*)((const u16*)src + (size_t)i * 8);
        else
            *(bf16x8*)(dst + (size_t)i * 8) = cvt8((const float*)src + (size_t)i * 8);
    }
}

// ---------------- 128x128 bf16 MFMA GEMM, global_load_lds staging (m97-class)
// C[i,n] = sum_k A[i,k]*W[n,k] (+bias). A,W are bf16 row-major [.,K].
// 4 waves 2x2, each owns 64x64 = 4x4 frags; 16 MFMA + 8 ds_read_b128 / K-step.
// LDS linear [128][32] bf16 per matrix (8 KB), staged via global_load_lds w=16:
// wave w stages 1KB chunks {2w,2w+1}: lane l -> row c*16 + (l>>2), kcol (l&3)*8.
// OMODE 0: qkv scatter (q->f32 qT, k->kB, v->vB transposed)
// OMODE 1: pos scatter (pB), row clamp to M-1, guard i<M
// OMODE 2: out = A@W^T + bias -> d_out (dtype per flag)
template<int OMODE>
__global__ __launch_bounds__(256) void gemm_mfma(
    const u16* __restrict__ A, const u16* __restrict__ Bw,
    const void* __restrict__ bias, const int* __restrict__ flags,
    float* __restrict__ qT, u16* __restrict__ kB, u16* __restrict__ vB,
    u16* __restrict__ pB, void* __restrict__ oout, int M, int N, int K)
{
    const bool isbf = (flags[0] != 0);
    __shared__ u16 As[128 * 32];   // linear, no pad (global_load_lds dest)
    __shared__ u16 Bs[128 * 32];
    const int tid = threadIdx.x;
    const int w = tid >> 6, lane = tid & 63;
    const int quad = lane >> 4, l16 = lane & 15;
    const int wr = w >> 1, wc = w & 1;
    const int bn = blockIdx.x * 128, bm = blockIdx.y * 128;
    const int c0 = w * 2, c1 = w * 2 + 1;            // this wave's chunks
    const int sr0 = c0 * 16 + (lane >> 2);           // staging rows
    const int sr1 = c1 * 16 + (lane >> 2);
    const int skoff = (lane & 3) * 8;                // k-offset (elements)

    f32x4 acc[4][4];
    #pragma unroll
    for (int m = 0; m < 4; m++)
        #pragma unroll
        for (int n = 0; n < 4; n++) {
            acc[m][n][0] = 0.f; acc[m][n][1] = 0.f;
            acc[m][n][2] = 0.f; acc[m][n][3] = 0.f;
        }

    for (int k0 = 0; k0 < K; k0 += 32) {
        int ar0 = bm + sr0, ar1 = bm + sr1;
        if (OMODE == 1) { ar0 = min(ar0, M - 1); ar1 = min(ar1, M - 1); }
        __syncthreads();   // previous-iter LDS reads complete before overwrite
        gload_lds16(A + (size_t)ar0 * K + k0 + skoff, As + c0 * 512);
        gload_lds16(A + (size_t)ar1 * K + k0 + skoff, As + c1 * 512);
        gload_lds16(Bw + (size_t)(bn + sr0) * K + k0 + skoff, Bs + c0 * 512);
        gload_lds16(Bw + (size_t)(bn + sr1) * K + k0 + skoff, Bs + c1 * 512);
        asm volatile("s_waitcnt vmcnt(0)" ::: "memory");
        __syncthreads();   // all staging visible

        bf16x8 af[4], bfr[4];
        #pragma unroll
        for (int m = 0; m < 4; m++)
            af[m] = *(const bf16x8*)&As[(wr * 64 + m * 16 + l16) * 32 + quad * 8];
        #pragma unroll
        for (int n = 0; n < 4; n++)
            bfr[n] = *(const bf16x8*)&Bs[(wc * 64 + n * 16 + l16) * 32 + quad * 8];
        #pragma unroll
        for (int m = 0; m < 4; m++)
            #pragma unroll
            for (int n = 0; n < 4; n++)
                acc[m][n] = MFMA16(af[m], bfr[n], acc[m][n]);
    }

    #pragma unroll
    for (int m = 0; m < 4; m++)
        #pragma unroll
        for (int nn = 0; nn < 4; nn++)
            #pragma unroll
            for (int rr = 0; rr < 4; rr++) {
                const int i = bm + wr * 64 + m * 16 + quad * 4 + rr;
                const int n = bn + wc * 64 + nn * 16 + l16;
                float val = acc[m][nn][rr];
                if (OMODE == 0) {
                    val += isbf ? us2f(((const u16*)bias)[n]) : ((const float*)bias)[n];
                    const int sec = n >> 10, w_ = n & 1023;
                    const int h_ = w_ >> 6, d_ = w_ & 63;
                    const size_t bh_ = (size_t)((i >> 9) * HH + h_);
                    const int t_ = i & 511;
                    if (sec == 0) qT[((bh_ * TT + t_) << 6) + d_] = val;
                    else if (sec == 1) kB[((bh_ * TT + t_) << 6) + d_] = f2us(val);
                    else vB[((bh_ * DKK + d_) << 9) + t_] = f2us(val);
                } else if (OMODE == 1) {
                    if (i < M) {
                        const int h_ = n >> 6, d_ = n & 63;
                        pB[((size_t)(h_ * 1024 + i) << 6) + d_] = f2us(val);
                    }
                } else {
                    val += isbf ? us2f(((const u16*)bias)[n]) : ((const float*)bias)[n];
                    if (isbf) ((u16*)oout)[(size_t)i * N + n] = f2us(val);
                    else ((float*)oout)[(size_t)i * N + n] = val;
                }
            }
}

// ---------------- MFMA attention: grid = (b, h, t-tile), b on blockIdx.x
// (XCD-pinned batches: FETCH 92.6 -> 61.9 MB measured r12; LDS 34.3 KB r14).
// ctx now written as bf16 TOKEN-major into ctxB so gemm<2> is a standard
// row-major bf16 GEMM (numerically identical: ctx was bf16-converted there).
__global__ __launch_bounds__(256) void attn_mfma(
    float* __restrict__ qT, const u16* __restrict__ kB, const u16* __restrict__ vB,
    const u16* __restrict__ pB, const void* __restrict__ posu,
    const void* __restrict__ posv, const unsigned int* __restrict__ pmask,
    void* __restrict__ d_out, u16* __restrict__ ctxB, const int* __restrict__ flags)
{
    const int b = blockIdx.x;
    const int h = blockIdx.y;
    const int t0 = blockIdx.z << 6;
    const int tid = threadIdx.x;
    const int w = tid >> 6, lane = tid & 63;
    const int quad = lane >> 4, l16 = lane & 15;
    const bool isbf = (flags[0] != 0);
    const size_t bh = (size_t)b * HH + h;

    __shared__ u16 wls[4][16][268];          // per-wave tile: bd f32 scratch / half-weights
    u16* wme = &wls[w][0][0];
    float* bdw = (float*)wme;                // [16][84] f32 scratch, per-wave (skewed)

    // ---- packed mask words (4 coalesced u32 loads/thread, hoisted early)
    const int trow = t0 + w * 16 + quad * 4;
    unsigned int mrow[4];
    #pragma unroll
    for (int r = 0; r < 4; r++)
        mrow[r] = pmask[((size_t)(b * TT + trow + r) << 4) + l16];

    // ---- A fragments q_u, q_v (prescaled by 0.125 so scores come out /8)
    const int myrow = t0 + w * 16 + l16;
    const float* qrow = qT + ((bh * TT + myrow) << 6);
    bf16x8 aU[2], aV[2];
    #pragma unroll
    for (int f = 0; f < 2; f++) {
        const int d0 = f * 32 + quad * 8;
        float q8[8], pu8[8], pv8[8];
        *(float4*)&q8[0] = *(const float4*)(qrow + d0);
        *(float4*)&q8[4] = *(const float4*)(qrow + d0 + 4);
        if (isbf) {
            const u16* puP = (const u16*)posu + h * 64 + d0;
            const u16* pvP = (const u16*)posv + h * 64 + d0;
            #pragma unroll
            for (int j = 0; j < 8; j++) { pu8[j] = us2f(puP[j]); pv8[j] = us2f(pvP[j]); }
        } else {
            const float* puP = (const float*)posu + h * 64 + d0;
            const float* pvP = (const float*)posv + h * 64 + d0;
            #pragma unroll
            for (int j = 0; j < 8; j++) { pu8[j] = puP[j]; pv8[j] = pvP[j]; }
        }
        #pragma unroll
        for (int j = 0; j < 8; j++) {
            aU[f][j] = (short)f2us((q8[j] + pu8[j]) * 0.125f);
            aV[f][j] = (short)f2us((q8[j] + pv8[j]) * 0.125f);
        }
    }

    // ---- AC scores: S[32] covers 512 cols (s)
    f32x4 S[32];
    #pragma unroll
    for (int ct = 0; ct < 32; ct++) { S[ct][0] = 0.f; S[ct][1] = 0.f; S[ct][2] = 0.f; S[ct][3] = 0.f; }
    const u16* kbase = kB + ((bh * TT) << 6) + quad * 8;
    #pragma unroll
    for (int ct = 0; ct < 32; ct++) {
        const u16* kp = kbase + ((size_t)(ct * 16 + l16) << 6);
        bf16x8 b0 = *(const bf16x8*)kp;
        bf16x8 b1 = *(const bf16x8*)(kp + 32);
        S[ct] = MFMA16(aU[0], b0, S[ct]);
        S[ct] = MFMA16(aU[1], b1, S[ct]);
    }

    // ---- BD: 8 chunks of 64 cols; per-wave 16x80 tile via LDS, skewed gather
    const u16* pbaseh = pB + ((size_t)h << 16);  // h stride = 1024 rows * 64
    for (int g = 0; g < 8; g++) {
        const int pb = g * 64 - t0 + 496 - w * 16;  // P row for c_local=0 (>=0, <=944)
        #pragma unroll
        for (int c5 = 0; c5 < 5; c5++) {
            const u16* pp = pbaseh + ((size_t)(pb + c5 * 16 + l16) << 6) + quad * 8;
            bf16x8 b0 = *(const bf16x8*)pp;
            bf16x8 b1 = *(const bf16x8*)(pp + 32);
            f32x4 c; c[0] = 0.f; c[1] = 0.f; c[2] = 0.f; c[3] = 0.f;
            c = MFMA16(aV[0], b0, c);
            c = MFMA16(aV[1], b1, c);
            #pragma unroll
            for (int r = 0; r < 4; r++)
                bdw[(quad * 4 + r) * 84 + c5 * 16 + l16] = c[r];
        }
        WAVE_SYNC();   // per-wave write->read visibility; WAR handled by in-order DS
        #pragma unroll
        for (int f = 0; f < 4; f++) {
            const int sc = f * 16 + l16;
            #pragma unroll
            for (int r = 0; r < 4; r++) {
                const int local = quad * 4 + r;
                // bd[local][sc + 15 - local]
                S[g * 4 + f][r] += bdw[local * 83 + sc + 15];
            }
        }
    }

    // ---- mask (bit test, no memory traffic)
    #pragma unroll
    for (int ct = 0; ct < 32; ct++) {
        #pragma unroll
        for (int r = 0; r < 4; r++) {
            if (!(mrow[r] & (1u << ct))) S[ct][r] = -100000.0f;
        }
    }

    // ---- softmax (rows live across 16 lanes of this quad)
    float mx[4] = {-3.0e38f, -3.0e38f, -3.0e38f, -3.0e38f};
    float sm[4] = {0.f, 0.f, 0.f, 0.f};
    #pragma unroll
    for (int ct = 0; ct < 32; ct++)
        #pragma unroll
        for (int r = 0; r < 4; r++) mx[r] = fmaxf(mx[r], S[ct][r]);
    #pragma unroll
    for (int r = 0; r < 4; r++)
        #pragma unroll
        for (int off = 1; off < 16; off <<= 1) mx[r] = fmaxf(mx[r], __shfl_xor(mx[r], off, 64));
    #pragma unroll
    for (int ct = 0; ct < 32; ct++)
        #pragma unroll
        for (int r = 0; r < 4; r++) {
            float e = __expf(S[ct][r] - mx[r]);
            S[ct][r] = e;
            sm[r] += e;
        }
    #pragma unroll
    for (int r = 0; r < 4; r++) {
        #pragma unroll
        for (int off = 1; off < 16; off <<= 1) sm[r] += __shfl_xor(sm[r], off, 64);
        sm[r] = 1.0f / sm[r];
    }

    // ---- weights + PV in TWO 256-col passes (LDS halved; measured r14)
    f32x4 Cv[4];
    #pragma unroll
    for (int i = 0; i < 4; i++) { Cv[i][0] = 0.f; Cv[i][1] = 0.f; Cv[i][2] = 0.f; Cv[i][3] = 0.f; }
    const u16* vb0 = vB + ((bh * DKK) << 9) + quad * 8;
    const size_t wbase = (size_t)BB * TT * DD + (((bh * TT + trow)) << 9) + l16;

    #pragma unroll
    for (int p = 0; p < 2; p++) {
        #pragma unroll
        for (int cl = 0; cl < 16; cl++) {
            const int ct = p * 16 + cl;
            #pragma unroll
            for (int r = 0; r < 4; r++) {
                const float wv = S[ct][r] * sm[r];
                wls[w][quad * 4 + r][cl * 16 + l16] = f2us(wv);
                if (!isbf) ((float*)d_out)[wbase + ((size_t)r << 9) + ct * 16] = wv;
            }
        }
        WAVE_SYNC();
        if (isbf) {
            u16* wout = (u16*)d_out + (size_t)BB * TT * DD + ((bh * TT + t0 + w * 16) << 9) + p * 256;
            const int sr = lane >> 5, sc8 = (lane & 31) * 8;
            #pragma unroll
            for (int rr = 0; rr < 8; rr++) {
                bf16x8 vv = *(const bf16x8*)&wls[w][rr * 2 + sr][sc8];
                *(bf16x8*)(wout + ((size_t)(rr * 2 + sr) << 9) + sc8) = vv;
            }
        }
        #pragma unroll
        for (int kl = 0; kl < 8; kl++) {
            const int ks = p * 8 + kl;
            bf16x8 aw = *(const bf16x8*)&wls[w][l16][kl * 32 + quad * 8];
            #pragma unroll
            for (int ctd = 0; ctd < 4; ctd++) {
                const u16* vp = vb0 + ((size_t)(ctd * 16 + l16) << 9) + ks * 32;
                bf16x8 bv = *(const bf16x8*)vp;
                Cv[ctd] = MFMA16(aw, bv, Cv[ctd]);
            }
        }
        WAVE_SYNC();   // drain PV reads before next pass overwrites (order pin)
    }

    // ctx -> ctxB bf16 TOKEN-major [b*T + t][1024] (col = h*64 + d)
    u16* crow = ctxB + ((size_t)(b * TT + trow) << 10) + h * 64 + l16;
    #pragma unroll
    for (int ctd = 0; ctd < 4; ctd++)
        #pragma unroll
        for (int r = 0; r < 4; r++)
            crow[((size_t)r << 10) + ctd * 16] = f2us(Cv[ctd][r]);
}

extern "C" void kernel_launch(void* const* d_in, const int* in_sizes, int n_in,
                              void* d_out, int out_size, void* d_ws, size_t ws_size,
                              hipStream_t stream)
{
    const void* x    = d_in[0];
    const void* mask = d_in[1];
    const void* pos  = d_in[2];
    const void* Wqkv = d_in[3];
    const void* bqkv = d_in[4];
    const void* Wpos = d_in[5];
    const void* posu = d_in[6];
    const void* posv = d_in[7];
    const void* Wout = d_in[8];
    const void* bout = d_in[9];

    char* ws = (char*)d_ws;
    float* qT    = (float*)(ws + 0);                 // [B,H,T,64] f32 16 MiB
    u16*   kB    = (u16*)(ws + 16777216);            // [B,H,T,64] bf16 8 MiB
    u16*   vB    = (u16*)(ws + 25165824);            // [B,H,64,T] bf16 8 MiB (transposed)
    u16*   pB    = (u16*)(ws + 33554432);            // [H,1024,64] bf16 2 MiB
    int*   flags = (int*)(ws + 35651584);
    unsigned int* pmask = (unsigned int*)(ws + 35655680);  // 256 KiB
    u16*   xB    = (u16*)(ws + 35917824);            // [4096,1024] bf16 8 MiB
    u16*   WqkvB = (u16*)(ws + 44306432);            // [3072,1024] bf16 6 MiB
    u16*   WposB = (u16*)(ws + 50597888);            // [1024,1024] bf16 2 MiB
    u16*   posB  = (u16*)(ws + 52695040);            // [1023,1024] bf16 2 MiB
    u16*   WoutB = (u16*)(ws + 54792192);            // [1024,1024] bf16 2 MiB
    u16*   ctxB  = xB;                               // aliases xB (dead after gemm<0>)

    detect_kernel<<<1, 64, 0, stream>>>((const u16*)Wqkv, (const unsigned int*)mask, flags);
    pack_mask<<<dim3(256), 256, 0, stream>>>(mask, pmask, flags);

    // 0) one-shot bf16 conversion of all GEMM inputs
    cvt_bf16<<<dim3(1024), 256, 0, stream>>>(x,    xB,    4096 * 1024 / 8, flags);
    cvt_bf16<<<dim3(1024), 256, 0, stream>>>(Wqkv, WqkvB, 3072 * 1024 / 8, flags);
    cvt_bf16<<<dim3(512),  256, 0, stream>>>(Wpos, WposB, 1024 * 1024 / 8, flags);
    cvt_bf16<<<dim3(512),  256, 0, stream>>>(pos,  posB,  1023 * 1024 / 8, flags);
    cvt_bf16<<<dim3(512),  256, 0, stream>>>(Wout, WoutB, 1024 * 1024 / 8, flags);

    // 1) qkv = x @ Wqkv^T + bqkv -> q(f32 qT), k(kB), v(vB transposed)
    gemm_mfma<0><<<dim3(24, 32), 256, 0, stream>>>(
        xB, WqkvB, bqkv, flags, qT, kB, vB, pB, nullptr, BB * TT, 3 * DD, DD);

    // 2) p = pos @ Wpos^T -> pB
    gemm_mfma<1><<<dim3(8, 8), 256, 0, stream>>>(
        posB, WposB, nullptr, flags, qT, kB, vB, pB, nullptr, SS, DD, DD);

    // 3) attention (b on x => XCD-pinned batches): weights -> d_out, ctx -> ctxB
    attn_mfma<<<dim3(BB, HH, 8), 256, 0, stream>>>(
        qT, kB, vB, pB, posu, posv, pmask, d_out, ctxB, flags);

    // 4) out = ctx @ Wout^T + bout
    gemm_mfma<2><<<dim3(8, 32), 256, 0, stream>>>(
        ctxB, WoutB, bout, flags, qT, kB, vB, pB, d_out, BB * TT, DD, DD);
}

// Round 19
// 438.833 us; speedup vs baseline: 1.1702x; 1.0087x over previous
//
#include <hip/hip_runtime.h>

#define BB 8
#define TT 512
#define DD 1024
#define HH 16
#define DKK 64
#define SS 1023

typedef unsigned short u16;
typedef __attribute__((ext_vector_type(8))) short bf16x8;
typedef __attribute__((ext_vector_type(4))) float f32x4;

#define MFMA16(a, b, c) __builtin_amdgcn_mfma_f32_16x16x32_bf16((a), (b), (c), 0, 0, 0)

// Wave-local LDS fence (attn only; all attn LDS is per-wave)
#define WAVE_SYNC() do { asm volatile("s_waitcnt lgkmcnt(0)" ::: "memory"); __builtin_amdgcn_sched_barrier(0); } while (0)

__device__ __forceinline__ float us2f(u16 u) {
    unsigned int x = ((unsigned int)u) << 16;
    return __uint_as_float(x);
}
__device__ __forceinline__ u16 f2us(float f) {
    unsigned int x = __float_as_uint(f);
    unsigned int lsb = (x >> 16) & 1u;
    x += 0x7fffu + lsb;
    return (u16)(x >> 16);
}
__device__ __forceinline__ bf16x8 cvt8(const float* p) {
    float4 f1 = *(const float4*)p;
    float4 f2 = *(const float4*)(p + 4);
    bf16x8 r;
    r[0] = (short)f2us(f1.x); r[1] = (short)f2us(f1.y);
    r[2] = (short)f2us(f1.z); r[3] = (short)f2us(f1.w);
    r[4] = (short)f2us(f2.x); r[5] = (short)f2us(f2.y);
    r[6] = (short)f2us(f2.z); r[7] = (short)f2us(f2.w);
    return r;
}
__device__ __forceinline__ void gload_lds16(const u16* g, u16* l) {
    __builtin_amdgcn_global_load_lds(
        (const __attribute__((address_space(1))) void*)g,
        (__attribute__((address_space(3))) void*)l, 16, 0, 0);
}

// flags[0] = 1 if float buffers are bf16, 0 if f32
// flags[1] = 1 if mask is int32, 0 if int8/bool
__global__ void detect_kernel(const u16* __restrict__ w,
                              const unsigned int* __restrict__ mask,
                              int* __restrict__ flags) {
    if (threadIdx.x == 0 && blockIdx.x == 0) {
        int plaus = 0;
        for (int i = 0; i < 256; i++) {
            u16 hw = w[i];
            int e = (hw >> 7) & 0xFF;
            if (e == 0 || (e >= 87 && e <= 131)) plaus++;
        }
        flags[0] = (plaus >= 205) ? 1 : 0;
        int ok = 1;
        for (int i = 0; i < 64; i++) if (mask[i] > 1u) ok = 0;
        flags[1] = ok;
    }
}

// Pack mask into bits: packed[(b*T + t)*16 + g], bit k = mask[b][t][k*16 + g].
__global__ __launch_bounds__(256) void pack_mask(const void* __restrict__ mask,
                                                 unsigned int* __restrict__ packed,
                                                 const int* __restrict__ flags) {
    const int idx = blockIdx.x * 256 + threadIdx.x;   // 8*512*16 = 65536 words
    const int g = idx & 15;
    const size_t bt = (size_t)(idx >> 4);
    unsigned int bits = 0;
    if (flags[1]) {
        const int* mp = (const int*)mask + bt * TT + g;
        #pragma unroll
        for (int k = 0; k < 32; k++) if (mp[k * 16] != 0) bits |= (1u << k);
    } else {
        const signed char* mp = (const signed char*)mask + bt * TT + g;
        #pragma unroll
        for (int k = 0; k < 32; k++) if (mp[k * 16] != 0) bits |= (1u << k);
    }
    packed[idx] = bits;
}

// One launch: convert/copy all 5 GEMM inputs to bf16 workspace buffers.
__global__ __launch_bounds__(256) void cvt_all(
    const void* __restrict__ s0, u16* __restrict__ d0, int n0,
    const void* __restrict__ s1, u16* __restrict__ d1, int n1,
    const void* __restrict__ s2, u16* __restrict__ d2, int n2,
    const void* __restrict__ s3, u16* __restrict__ d3, int n3,
    const void* __restrict__ s4, u16* __restrict__ d4, int n4,
    const int* __restrict__ flags)
{
    const bool isbf = (flags[0] != 0);
    const int total = n0 + n1 + n2 + n3 + n4;
    for (int i = blockIdx.x * 256 + threadIdx.x; i < total; i += gridDim.x * 256) {
        const void* s; u16* d; int j = i;
        if (j < n0) { s = s0; d = d0; }
        else { j -= n0;
            if (j < n1) { s = s1; d = d1; }
            else { j -= n1;
                if (j < n2) { s = s2; d = d2; }
                else { j -= n2;
                    if (j < n3) { s = s3; d = d3; }
                    else { j -= n3; s = s4; d = d4; }
                }
            }
        }
        if (isbf)
            *(bf16x8*)(d + (size_t)j * 8) = *(const bf16x8*)((const u16*)s + (size_t)j * 8);
        else
            *(bf16x8*)(d + (size_t)j * 8) = cvt8((const float*)s + (size_t)j * 8);
    }
}

// ---------------- 128x128 bf16 MFMA GEMM, double-buffered global_load_lds
// (2-phase pipeline, catalog T3-minimum): STAGE(t+1) issued BEFORE compute(t),
// one vmcnt(0)+barrier per K-tile -> next tile's HBM latency hides under MFMA.
// 4 waves 2x2, each owns 64x64 = 4x4 frags; 16 MFMA + 8 ds_read_b128 / K-step.
// OMODE 0: qkv scatter (q->f32 qT, k->kB, v->vB transposed)
// OMODE 1: pos scatter (pB), row clamp to M-1, guard i<M
// OMODE 2: out = A@W^T + bias -> d_out (dtype per flag)
template<int OMODE>
__global__ __launch_bounds__(256) void gemm_mfma(
    const u16* __restrict__ A, const u16* __restrict__ Bw,
    const void* __restrict__ bias, const int* __restrict__ flags,
    float* __restrict__ qT, u16* __restrict__ kB, u16* __restrict__ vB,
    u16* __restrict__ pB, void* __restrict__ oout, int M, int N, int K)
{
    const bool isbf = (flags[0] != 0);
    __shared__ u16 As[2][128 * 32];   // linear, no pad (global_load_lds dest)
    __shared__ u16 Bs[2][128 * 32];
    const int tid = threadIdx.x;
    const int w = tid >> 6, lane = tid & 63;
    const int quad = lane >> 4, l16 = lane & 15;
    const int wr = w >> 1, wc = w & 1;
    const int bn = blockIdx.x * 128, bm = blockIdx.y * 128;
    const int c0 = w * 2, c1 = w * 2 + 1;            // this wave's chunks
    int ar0 = bm + c0 * 16 + (lane >> 2);            // staging rows
    int ar1 = bm + c1 * 16 + (lane >> 2);
    if (OMODE == 1) { ar0 = min(ar0, M - 1); ar1 = min(ar1, M - 1); }
    const int br0 = bn + c0 * 16 + (lane >> 2);
    const int br1 = bn + c1 * 16 + (lane >> 2);
    const int skoff = (lane & 3) * 8;                // k-offset (elements)

    f32x4 acc[4][4];
    #pragma unroll
    for (int m = 0; m < 4; m++)
        #pragma unroll
        for (int n = 0; n < 4; n++) {
            acc[m][n][0] = 0.f; acc[m][n][1] = 0.f;
            acc[m][n][2] = 0.f; acc[m][n][3] = 0.f;
        }

    // prologue: stage tile 0
    gload_lds16(A + (size_t)ar0 * K + skoff, &As[0][c0 * 512]);
    gload_lds16(A + (size_t)ar1 * K + skoff, &As[0][c1 * 512]);
    gload_lds16(Bw + (size_t)br0 * K + skoff, &Bs[0][c0 * 512]);
    gload_lds16(Bw + (size_t)br1 * K + skoff, &Bs[0][c1 * 512]);
    asm volatile("s_waitcnt vmcnt(0)" ::: "memory");
    __syncthreads();

    const int nt = K >> 5;
    int cur = 0;
    for (int t = 0; t < nt; ++t) {
        if (t + 1 < nt) {
            const int kn = (t + 1) << 5;
            gload_lds16(A + (size_t)ar0 * K + kn + skoff, &As[cur ^ 1][c0 * 512]);
            gload_lds16(A + (size_t)ar1 * K + kn + skoff, &As[cur ^ 1][c1 * 512]);
            gload_lds16(Bw + (size_t)br0 * K + kn + skoff, &Bs[cur ^ 1][c0 * 512]);
            gload_lds16(Bw + (size_t)br1 * K + kn + skoff, &Bs[cur ^ 1][c1 * 512]);
        }
        bf16x8 af[4], bfr[4];
        #pragma unroll
        for (int m = 0; m < 4; m++)
            af[m] = *(const bf16x8*)&As[cur][(wr * 64 + m * 16 + l16) * 32 + quad * 8];
        #pragma unroll
        for (int n = 0; n < 4; n++)
            bfr[n] = *(const bf16x8*)&Bs[cur][(wc * 64 + n * 16 + l16) * 32 + quad * 8];
        #pragma unroll
        for (int m = 0; m < 4; m++)
            #pragma unroll
            for (int n = 0; n < 4; n++)
                acc[m][n] = MFMA16(af[m], bfr[n], acc[m][n]);
        if (t + 1 < nt) {
            asm volatile("s_waitcnt vmcnt(0)" ::: "memory");
            __syncthreads();
            cur ^= 1;
        }
    }

    #pragma unroll
    for (int m = 0; m < 4; m++)
        #pragma unroll
        for (int nn = 0; nn < 4; nn++)
            #pragma unroll
            for (int rr = 0; rr < 4; rr++) {
                const int i = bm + wr * 64 + m * 16 + quad * 4 + rr;
                const int n = bn + wc * 64 + nn * 16 + l16;
                float val = acc[m][nn][rr];
                if (OMODE == 0) {
                    val += isbf ? us2f(((const u16*)bias)[n]) : ((const float*)bias)[n];
                    const int sec = n >> 10, w_ = n & 1023;
                    const int h_ = w_ >> 6, d_ = w_ & 63;
                    const size_t bh_ = (size_t)((i >> 9) * HH + h_);
                    const int t_ = i & 511;
                    if (sec == 0) qT[((bh_ * TT + t_) << 6) + d_] = val;
                    else if (sec == 1) kB[((bh_ * TT + t_) << 6) + d_] = f2us(val);
                    else vB[((bh_ * DKK + d_) << 9) + t_] = f2us(val);
                } else if (OMODE == 1) {
                    if (i < M) {
                        const int h_ = n >> 6, d_ = n & 63;
                        pB[((size_t)(h_ * 1024 + i) << 6) + d_] = f2us(val);
                    }
                } else {
                    val += isbf ? us2f(((const u16*)bias)[n]) : ((const float*)bias)[n];
                    if (isbf) ((u16*)oout)[(size_t)i * N + n] = f2us(val);
                    else ((float*)oout)[(size_t)i * N + n] = val;
                }
            }
}

// ---------------- MFMA attention: grid = (b, h, t-tile), b on blockIdx.x
// (XCD-pinned batches: FETCH 92.6 -> 61.9 MB measured r12; LDS 34.3 KB r14;
//  bf16 token-major ctx -> WRITE -8 MB measured r17).
__global__ __launch_bounds__(256) void attn_mfma(
    float* __restrict__ qT, const u16* __restrict__ kB, const u16* __restrict__ vB,
    const u16* __restrict__ pB, const void* __restrict__ posu,
    const void* __restrict__ posv, const unsigned int* __restrict__ pmask,
    void* __restrict__ d_out, u16* __restrict__ ctxB, const int* __restrict__ flags)
{
    const int b = blockIdx.x;
    const int h = blockIdx.y;
    const int t0 = blockIdx.z << 6;
    const int tid = threadIdx.x;
    const int w = tid >> 6, lane = tid & 63;
    const int quad = lane >> 4, l16 = lane & 15;
    const bool isbf = (flags[0] != 0);
    const size_t bh = (size_t)b * HH + h;

    __shared__ u16 wls[4][16][268];          // per-wave tile: bd f32 scratch / half-weights
    u16* wme = &wls[w][0][0];
    float* bdw = (float*)wme;                // [16][84] f32 scratch, per-wave (skewed)

    // ---- packed mask words (4 coalesced u32 loads/thread, hoisted early)
    const int trow = t0 + w * 16 + quad * 4;
    unsigned int mrow[4];
    #pragma unroll
    for (int r = 0; r < 4; r++)
        mrow[r] = pmask[((size_t)(b * TT + trow + r) << 4) + l16];

    // ---- A fragments q_u, q_v (prescaled by 0.125 so scores come out /8)
    const int myrow = t0 + w * 16 + l16;
    const float* qrow = qT + ((bh * TT + myrow) << 6);
    bf16x8 aU[2], aV[2];
    #pragma unroll
    for (int f = 0; f < 2; f++) {
        const int d0 = f * 32 + quad * 8;
        float q8[8], pu8[8], pv8[8];
        *(float4*)&q8[0] = *(const float4*)(qrow + d0);
        *(float4*)&q8[4] = *(const float4*)(qrow + d0 + 4);
        if (isbf) {
            const u16* puP = (const u16*)posu + h * 64 + d0;
            const u16* pvP = (const u16*)posv + h * 64 + d0;
            #pragma unroll
            for (int j = 0; j < 8; j++) { pu8[j] = us2f(puP[j]); pv8[j] = us2f(pvP[j]); }
        } else {
            const float* puP = (const float*)posu + h * 64 + d0;
            const float* pvP = (const float*)posv + h * 64 + d0;
            #pragma unroll
            for (int j = 0; j < 8; j++) { pu8[j] = puP[j]; pv8[j] = pvP[j]; }
        }
        #pragma unroll
        for (int j = 0; j < 8; j++) {
            aU[f][j] = (short)f2us((q8[j] + pu8[j]) * 0.125f);
            aV[f][j] = (short)f2us((q8[j] + pv8[j]) * 0.125f);
        }
    }

    // ---- AC scores: S[32] covers 512 cols (s)
    f32x4 S[32];
    #pragma unroll
    for (int ct = 0; ct < 32; ct++) { S[ct][0] = 0.f; S[ct][1] = 0.f; S[ct][2] = 0.f; S[ct][3] = 0.f; }
    const u16* kbase = kB + ((bh * TT) << 6) + quad * 8;
    #pragma unroll
    for (int ct = 0; ct < 32; ct++) {
        const u16* kp = kbase + ((size_t)(ct * 16 + l16) << 6);
        bf16x8 b0 = *(const bf16x8*)kp;
        bf16x8 b1 = *(const bf16x8*)(kp + 32);
        S[ct] = MFMA16(aU[0], b0, S[ct]);
        S[ct] = MFMA16(aU[1], b1, S[ct]);
    }

    // ---- BD: 8 chunks of 64 cols; per-wave 16x80 tile via LDS, skewed gather
    const u16* pbaseh = pB + ((size_t)h << 16);  // h stride = 1024 rows * 64
    for (int g = 0; g < 8; g++) {
        const int pb = g * 64 - t0 + 496 - w * 16;  // P row for c_local=0 (>=0, <=944)
        #pragma unroll
        for (int c5 = 0; c5 < 5; c5++) {
            const u16* pp = pbaseh + ((size_t)(pb + c5 * 16 + l16) << 6) + quad * 8;
            bf16x8 b0 = *(const bf16x8*)pp;
            bf16x8 b1 = *(const bf16x8*)(pp + 32);
            f32x4 c; c[0] = 0.f; c[1] = 0.f; c[2] = 0.f; c[3] = 0.f;
            c = MFMA16(aV[0], b0, c);
            c = MFMA16(aV[1], b1, c);
            #pragma unroll
            for (int r = 0; r < 4; r++)
                bdw[(quad * 4 + r) * 84 + c5 * 16 + l16] = c[r];
        }
        WAVE_SYNC();   // per-wave write->read visibility; WAR handled by in-order DS
        #pragma unroll
        for (int f = 0; f < 4; f++) {
            const int sc = f * 16 + l16;
            #pragma unroll
            for (int r = 0; r < 4; r++) {
                const int local = quad * 4 + r;
                // bd[local][sc + 15 - local]
                S[g * 4 + f][r] += bdw[local * 83 + sc + 15];
            }
        }
    }

    // ---- mask (bit test, no memory traffic)
    #pragma unroll
    for (int ct = 0; ct < 32; ct++) {
        #pragma unroll
        for (int r = 0; r < 4; r++) {
            if (!(mrow[r] & (1u << ct))) S[ct][r] = -100000.0f;
        }
    }

    // ---- softmax (rows live across 16 lanes of this quad)
    float mx[4] = {-3.0e38f, -3.0e38f, -3.0e38f, -3.0e38f};
    float sm[4] = {0.f, 0.f, 0.f, 0.f};
    #pragma unroll
    for (int ct = 0; ct < 32; ct++)
        #pragma unroll
        for (int r = 0; r < 4; r++) mx[r] = fmaxf(mx[r], S[ct][r]);
    #pragma unroll
    for (int r = 0; r < 4; r++)
        #pragma unroll
        for (int off = 1; off < 16; off <<= 1) mx[r] = fmaxf(mx[r], __shfl_xor(mx[r], off, 64));
    #pragma unroll
    for (int ct = 0; ct < 32; ct++)
        #pragma unroll
        for (int r = 0; r < 4; r++) {
            float e = __expf(S[ct][r] - mx[r]);
            S[ct][r] = e;
            sm[r] += e;
        }
    #pragma unroll
    for (int r = 0; r < 4; r++) {
        #pragma unroll
        for (int off = 1; off < 16; off <<= 1) sm[r] += __shfl_xor(sm[r], off, 64);
        sm[r] = 1.0f / sm[r];
    }

    // ---- weights + PV in TWO 256-col passes (LDS halved; measured r14)
    f32x4 Cv[4];
    #pragma unroll
    for (int i = 0; i < 4; i++) { Cv[i][0] = 0.f; Cv[i][1] = 0.f; Cv[i][2] = 0.f; Cv[i][3] = 0.f; }
    const u16* vb0 = vB + ((bh * DKK) << 9) + quad * 8;
    const size_t wbase = (size_t)BB * TT * DD + (((bh * TT + trow)) << 9) + l16;

    #pragma unroll
    for (int p = 0; p < 2; p++) {
        #pragma unroll
        for (int cl = 0; cl < 16; cl++) {
            const int ct = p * 16 + cl;
            #pragma unroll
            for (int r = 0; r < 4; r++) {
                const float wv = S[ct][r] * sm[r];
                wls[w][quad * 4 + r][cl * 16 + l16] = f2us(wv);
                if (!isbf) ((float*)d_out)[wbase + ((size_t)r << 9) + ct * 16] = wv;
            }
        }
        WAVE_SYNC();
        if (isbf) {
            u16* wout = (u16*)d_out + (size_t)BB * TT * DD + ((bh * TT + t0 + w * 16) << 9) + p * 256;
            const int sr = lane >> 5, sc8 = (lane & 31) * 8;
            #pragma unroll
            for (int rr = 0; rr < 8; rr++) {
                bf16x8 vv = *(const bf16x8*)&wls[w][rr * 2 + sr][sc8];
                *(bf16x8*)(wout + ((size_t)(rr * 2 + sr) << 9) + sc8) = vv;
            }
        }
        #pragma unroll
        for (int kl = 0; kl < 8; kl++) {
            const int ks = p * 8 + kl;
            bf16x8 aw = *(const bf16x8*)&wls[w][l16][kl * 32 + quad * 8];
            #pragma unroll
            for (int ctd = 0; ctd < 4; ctd++) {
                const u16* vp = vb0 + ((size_t)(ctd * 16 + l16) << 9) + ks * 32;
                bf16x8 bv = *(const bf16x8*)vp;
                Cv[ctd] = MFMA16(aw, bv, Cv[ctd]);
            }
        }
        WAVE_SYNC();   // drain PV reads before next pass overwrites (order pin)
    }

    // ctx -> ctxB bf16 TOKEN-major [b*T + t][1024] (col = h*64 + d)
    u16* crow = ctxB + ((size_t)(b * TT + trow) << 10) + h * 64 + l16;
    #pragma unroll
    for (int ctd = 0; ctd < 4; ctd++)
        #pragma unroll
        for (int r = 0; r < 4; r++)
            crow[((size_t)r << 10) + ctd * 16] = f2us(Cv[ctd][r]);
}

extern "C" void kernel_launch(void* const* d_in, const int* in_sizes, int n_in,
                              void* d_out, int out_size, void* d_ws, size_t ws_size,
                              hipStream_t stream)
{
    const void* x    = d_in[0];
    const void* mask = d_in[1];
    const void* pos  = d_in[2];
    const void* Wqkv = d_in[3];
    const void* bqkv = d_in[4];
    const void* Wpos = d_in[5];
    const void* posu = d_in[6];
    const void* posv = d_in[7];
    const void* Wout = d_in[8];
    const void* bout = d_in[9];

    char* ws = (char*)d_ws;
    float* qT    = (float*)(ws + 0);                 // [B,H,T,64] f32 16 MiB
    u16*   kB    = (u16*)(ws + 16777216);            // [B,H,T,64] bf16 8 MiB
    u16*   vB    = (u16*)(ws + 25165824);            // [B,H,64,T] bf16 8 MiB (transposed)
    u16*   pB    = (u16*)(ws + 33554432);            // [H,1024,64] bf16 2 MiB
    int*   flags = (int*)(ws + 35651584);
    unsigned int* pmask = (unsigned int*)(ws + 35655680);  // 256 KiB
    u16*   xB    = (u16*)(ws + 35917824);            // [4096,1024] bf16 8 MiB
    u16*   WqkvB = (u16*)(ws + 44306432);            // [3072,1024] bf16 6 MiB
    u16*   WposB = (u16*)(ws + 50597888);            // [1024,1024] bf16 2 MiB
    u16*   posB  = (u16*)(ws + 52695040);            // [1023,1024] bf16 2 MiB
    u16*   WoutB = (u16*)(ws + 54792192);            // [1024,1024] bf16 2 MiB
    u16*   ctxB  = xB;                               // aliases xB (dead after gemm<0>)

    detect_kernel<<<1, 64, 0, stream>>>((const u16*)Wqkv, (const unsigned int*)mask, flags);
    pack_mask<<<dim3(256), 256, 0, stream>>>(mask, pmask, flags);

    // 0) one-shot bf16 conversion of all GEMM inputs (single launch)
    cvt_all<<<dim3(2048), 256, 0, stream>>>(
        x, xB, 4096 * 1024 / 8,
        Wqkv, WqkvB, 3072 * 1024 / 8,
        Wpos, WposB, 1024 * 1024 / 8,
        pos, posB, 1023 * 1024 / 8,
        Wout, WoutB, 1024 * 1024 / 8,
        flags);

    // 1) qkv = x @ Wqkv^T + bqkv -> q(f32 qT), k(kB), v(vB transposed)
    gemm_mfma<0><<<dim3(24, 32), 256, 0, stream>>>(
        xB, WqkvB, bqkv, flags, qT, kB, vB, pB, nullptr, BB * TT, 3 * DD, DD);

    // 2) p = pos @ Wpos^T -> pB
    gemm_mfma<1><<<dim3(8, 8), 256, 0, stream>>>(
        posB, WposB, nullptr, flags, qT, kB, vB, pB, nullptr, SS, DD, DD);

    // 3) attention (b on x => XCD-pinned batches): weights -> d_out, ctx -> ctxB
    attn_mfma<<<dim3(BB, HH, 8), 256, 0, stream>>>(
        qT, kB, vB, pB, posu, posv, pmask, d_out, ctxB, flags);

    // 4) out = ctx @ Wout^T + bout
    gemm_mfma<2><<<dim3(8, 32), 256, 0, stream>>>(
        ctxB, WoutB, bout, flags, qT, kB, vB, pB, d_out, BB * TT, DD, DD);
}

// Round 21
// 429.518 us; speedup vs baseline: 1.1956x; 1.0217x over previous
//
#include <hip/hip_runtime.h>

#define BB 8
#define TT 512
#define DD 1024
#define HH 16
#define DKK 64
#define SS 1023

typedef unsigned short u16;
typedef __attribute__((ext_vector_type(8))) short bf16x8;
typedef __attribute__((ext_vector_type(4))) float f32x4;

#define MFMA16(a, b, c) __builtin_amdgcn_mfma_f32_16x16x32_bf16((a), (b), (c), 0, 0, 0)

// Wave-local LDS fence (attn only; all attn LDS is per-wave).
// NOTE (r20 post-mortem): this fence is LOAD-BEARING as a COMPILE-TIME
// ordering barrier — bdw (float*) and wls (u16*) type-pun the same LDS
// bytes, so without the "memory" clobber the compiler reorders ds_read
// above the producing ds_write (measured: absmax 0.188, r20).
#define WAVE_SYNC() do { asm volatile("s_waitcnt lgkmcnt(0)" ::: "memory"); __builtin_amdgcn_sched_barrier(0); } while (0)

__device__ __forceinline__ float us2f(u16 u) {
    unsigned int x = ((unsigned int)u) << 16;
    return __uint_as_float(x);
}
__device__ __forceinline__ u16 f2us(float f) {
    unsigned int x = __float_as_uint(f);
    unsigned int lsb = (x >> 16) & 1u;
    x += 0x7fffu + lsb;
    return (u16)(x >> 16);
}
__device__ __forceinline__ bf16x8 cvt8(const float* p) {
    float4 f1 = *(const float4*)p;
    float4 f2 = *(const float4*)(p + 4);
    bf16x8 r;
    r[0] = (short)f2us(f1.x); r[1] = (short)f2us(f1.y);
    r[2] = (short)f2us(f1.z); r[3] = (short)f2us(f1.w);
    r[4] = (short)f2us(f2.x); r[5] = (short)f2us(f2.y);
    r[6] = (short)f2us(f2.z); r[7] = (short)f2us(f2.w);
    return r;
}
__device__ __forceinline__ void gload_lds16(const u16* g, u16* l) {
    __builtin_amdgcn_global_load_lds(
        (const __attribute__((address_space(1))) void*)g,
        (__attribute__((address_space(3))) void*)l, 16, 0, 0);
}

// flags[0] = 1 if float buffers are bf16, 0 if f32
// flags[1] = 1 if mask is int32, 0 if int8/bool
__global__ void detect_kernel(const u16* __restrict__ w,
                              const unsigned int* __restrict__ mask,
                              int* __restrict__ flags) {
    if (threadIdx.x == 0 && blockIdx.x == 0) {
        int plaus = 0;
        for (int i = 0; i < 256; i++) {
            u16 hw = w[i];
            int e = (hw >> 7) & 0xFF;
            if (e == 0 || (e >= 87 && e <= 131)) plaus++;
        }
        flags[0] = (plaus >= 205) ? 1 : 0;
        int ok = 1;
        for (int i = 0; i < 64; i++) if (mask[i] > 1u) ok = 0;
        flags[1] = ok;
    }
}

// Pack mask into bits: packed[(b*T + t)*16 + g], bit k = mask[b][t][k*16 + g].
__global__ __launch_bounds__(256) void pack_mask(const void* __restrict__ mask,
                                                 unsigned int* __restrict__ packed,
                                                 const int* __restrict__ flags) {
    const int idx = blockIdx.x * 256 + threadIdx.x;   // 8*512*16 = 65536 words
    const int g = idx & 15;
    const size_t bt = (size_t)(idx >> 4);
    unsigned int bits = 0;
    if (flags[1]) {
        const int* mp = (const int*)mask + bt * TT + g;
        #pragma unroll
        for (int k = 0; k < 32; k++) if (mp[k * 16] != 0) bits |= (1u << k);
    } else {
        const signed char* mp = (const signed char*)mask + bt * TT + g;
        #pragma unroll
        for (int k = 0; k < 32; k++) if (mp[k * 16] != 0) bits |= (1u << k);
    }
    packed[idx] = bits;
}

// One launch: convert/copy all 5 GEMM inputs to bf16 workspace buffers.
__global__ __launch_bounds__(256) void cvt_all(
    const void* __restrict__ s0, u16* __restrict__ d0, int n0,
    const void* __restrict__ s1, u16* __restrict__ d1, int n1,
    const void* __restrict__ s2, u16* __restrict__ d2, int n2,
    const void* __restrict__ s3, u16* __restrict__ d3, int n3,
    const void* __restrict__ s4, u16* __restrict__ d4, int n4,
    const int* __restrict__ flags)
{
    const bool isbf = (flags[0] != 0);
    const int total = n0 + n1 + n2 + n3 + n4;
    for (int i = blockIdx.x * 256 + threadIdx.x; i < total; i += gridDim.x * 256) {
        const void* s; u16* d; int j = i;
        if (j < n0) { s = s0; d = d0; }
        else { j -= n0;
            if (j < n1) { s = s1; d = d1; }
            else { j -= n1;
                if (j < n2) { s = s2; d = d2; }
                else { j -= n2;
                    if (j < n3) { s = s3; d = d3; }
                    else { j -= n3; s = s4; d = d4; }
                }
            }
        }
        if (isbf)
            *(bf16x8*)(d + (size_t)j * 8) = *(const bf16x8*)((const u16*)s + (size_t)j * 8);
        else
            *(bf16x8*)(d + (size_t)j * 8) = cvt8((const float*)s + (size_t)j * 8);
    }
}

// ---------------- 128x128 bf16 MFMA GEMM, double-buffered global_load_lds
// (2-phase pipeline): STAGE(t+1) issued BEFORE compute(t), one vmcnt(0)+barrier
// per K-tile. 4 waves 2x2, 4x4 frags; 16 MFMA + 8 ds_read_b128 / K-step.
// OMODE 0: qkv scatter (q->f32 qT, k->kB, v->vB transposed)
// OMODE 1: pos scatter (pB), row clamp to M-1, guard i<M
// OMODE 2: out = A@W^T + bias -> d_out (dtype per flag)
template<int OMODE>
__global__ __launch_bounds__(256) void gemm_mfma(
    const u16* __restrict__ A, const u16* __restrict__ Bw,
    const void* __restrict__ bias, const int* __restrict__ flags,
    float* __restrict__ qT, u16* __restrict__ kB, u16* __restrict__ vB,
    u16* __restrict__ pB, void* __restrict__ oout, int M, int N, int K)
{
    const bool isbf = (flags[0] != 0);
    __shared__ u16 As[2][128 * 32];   // linear, no pad (global_load_lds dest)
    __shared__ u16 Bs[2][128 * 32];
    const int tid = threadIdx.x;
    const int w = tid >> 6, lane = tid & 63;
    const int quad = lane >> 4, l16 = lane & 15;
    const int wr = w >> 1, wc = w & 1;
    const int bn = blockIdx.x * 128, bm = blockIdx.y * 128;
    const int c0 = w * 2, c1 = w * 2 + 1;            // this wave's chunks
    int ar0 = bm + c0 * 16 + (lane >> 2);            // staging rows
    int ar1 = bm + c1 * 16 + (lane >> 2);
    if (OMODE == 1) { ar0 = min(ar0, M - 1); ar1 = min(ar1, M - 1); }
    const int br0 = bn + c0 * 16 + (lane >> 2);
    const int br1 = bn + c1 * 16 + (lane >> 2);
    const int skoff = (lane & 3) * 8;                // k-offset (elements)

    f32x4 acc[4][4];
    #pragma unroll
    for (int m = 0; m < 4; m++)
        #pragma unroll
        for (int n = 0; n < 4; n++) {
            acc[m][n][0] = 0.f; acc[m][n][1] = 0.f;
            acc[m][n][2] = 0.f; acc[m][n][3] = 0.f;
        }

    // prologue: stage tile 0
    gload_lds16(A + (size_t)ar0 * K + skoff, &As[0][c0 * 512]);
    gload_lds16(A + (size_t)ar1 * K + skoff, &As[0][c1 * 512]);
    gload_lds16(Bw + (size_t)br0 * K + skoff, &Bs[0][c0 * 512]);
    gload_lds16(Bw + (size_t)br1 * K + skoff, &Bs[0][c1 * 512]);
    asm volatile("s_waitcnt vmcnt(0)" ::: "memory");
    __syncthreads();

    const int nt = K >> 5;
    int cur = 0;
    for (int t = 0; t < nt; ++t) {
        if (t + 1 < nt) {
            const int kn = (t + 1) << 5;
            gload_lds16(A + (size_t)ar0 * K + kn + skoff, &As[cur ^ 1][c0 * 512]);
            gload_lds16(A + (size_t)ar1 * K + kn + skoff, &As[cur ^ 1][c1 * 512]);
            gload_lds16(Bw + (size_t)br0 * K + kn + skoff, &Bs[cur ^ 1][c0 * 512]);
            gload_lds16(Bw + (size_t)br1 * K + kn + skoff, &Bs[cur ^ 1][c1 * 512]);
        }
        bf16x8 af[4], bfr[4];
        #pragma unroll
        for (int m = 0; m < 4; m++)
            af[m] = *(const bf16x8*)&As[cur][(wr * 64 + m * 16 + l16) * 32 + quad * 8];
        #pragma unroll
        for (int n = 0; n < 4; n++)
            bfr[n] = *(const bf16x8*)&Bs[cur][(wc * 64 + n * 16 + l16) * 32 + quad * 8];
        #pragma unroll
        for (int m = 0; m < 4; m++)
            #pragma unroll
            for (int n = 0; n < 4; n++)
                acc[m][n] = MFMA16(af[m], bfr[n], acc[m][n]);
        if (t + 1 < nt) {
            asm volatile("s_waitcnt vmcnt(0)" ::: "memory");
            __syncthreads();
            cur ^= 1;
        }
    }

    #pragma unroll
    for (int m = 0; m < 4; m++)
        #pragma unroll
        for (int nn = 0; nn < 4; nn++)
            #pragma unroll
            for (int rr = 0; rr < 4; rr++) {
                const int i = bm + wr * 64 + m * 16 + quad * 4 + rr;
                const int n = bn + wc * 64 + nn * 16 + l16;
                float val = acc[m][nn][rr];
                if (OMODE == 0) {
                    val += isbf ? us2f(((const u16*)bias)[n]) : ((const float*)bias)[n];
                    const int sec = n >> 10, w_ = n & 1023;
                    const int h_ = w_ >> 6, d_ = w_ & 63;
                    const size_t bh_ = (size_t)((i >> 9) * HH + h_);
                    const int t_ = i & 511;
                    if (sec == 0) qT[((bh_ * TT + t_) << 6) + d_] = val;
                    else if (sec == 1) kB[((bh_ * TT + t_) << 6) + d_] = f2us(val);
                    else vB[((bh_ * DKK + d_) << 9) + t_] = f2us(val);
                } else if (OMODE == 1) {
                    if (i < M) {
                        const int h_ = n >> 6, d_ = n & 63;
                        pB[((size_t)(h_ * 1024 + i) << 6) + d_] = f2us(val);
                    }
                } else {
                    val += isbf ? us2f(((const u16*)bias)[n]) : ((const float*)bias)[n];
                    if (isbf) ((u16*)oout)[(size_t)i * N + n] = f2us(val);
                    else ((float*)oout)[(size_t)i * N + n] = val;
                }
            }
}

// ---------------- MFMA attention: grid = (b, h, t-tile), b on blockIdx.x
// (XCD-pinned batches: FETCH 92.6 -> 61.9 MB measured r12; LDS 34.3 KB r14;
//  bf16 token-major ctx -> WRITE -8 MB measured r17).
__global__ __launch_bounds__(256) void attn_mfma(
    float* __restrict__ qT, const u16* __restrict__ kB, const u16* __restrict__ vB,
    const u16* __restrict__ pB, const void* __restrict__ posu,
    const void* __restrict__ posv, const unsigned int* __restrict__ pmask,
    void* __restrict__ d_out, u16* __restrict__ ctxB, const int* __restrict__ flags)
{
    const int b = blockIdx.x;
    const int h = blockIdx.y;
    const int t0 = blockIdx.z << 6;
    const int tid = threadIdx.x;
    const int w = tid >> 6, lane = tid & 63;
    const int quad = lane >> 4, l16 = lane & 15;
    const bool isbf = (flags[0] != 0);
    const size_t bh = (size_t)b * HH + h;

    __shared__ u16 wls[4][16][268];          // per-wave tile: bd f32 scratch / half-weights
    u16* wme = &wls[w][0][0];
    float* bdw = (float*)wme;                // [16][84] f32 scratch, per-wave (skewed)

    // ---- packed mask words (4 coalesced u32 loads/thread, hoisted early)
    const int trow = t0 + w * 16 + quad * 4;
    unsigned int mrow[4];
    #pragma unroll
    for (int r = 0; r < 4; r++)
        mrow[r] = pmask[((size_t)(b * TT + trow + r) << 4) + l16];

    // ---- A fragments q_u, q_v (prescaled by 0.125 so scores come out /8)
    const int myrow = t0 + w * 16 + l16;
    const float* qrow = qT + ((bh * TT + myrow) << 6);
    bf16x8 aU[2], aV[2];
    #pragma unroll
    for (int f = 0; f < 2; f++) {
        const int d0 = f * 32 + quad * 8;
        float q8[8], pu8[8], pv8[8];
        *(float4*)&q8[0] = *(const float4*)(qrow + d0);
        *(float4*)&q8[4] = *(const float4*)(qrow + d0 + 4);
        if (isbf) {
            const u16* puP = (const u16*)posu + h * 64 + d0;
            const u16* pvP = (const u16*)posv + h * 64 + d0;
            #pragma unroll
            for (int j = 0; j < 8; j++) { pu8[j] = us2f(puP[j]); pv8[j] = us2f(pvP[j]); }
        } else {
            const float* puP = (const float*)posu + h * 64 + d0;
            const float* pvP = (const float*)posv + h * 64 + d0;
            #pragma unroll
            for (int j = 0; j < 8; j++) { pu8[j] = puP[j]; pv8[j] = pvP[j]; }
        }
        #pragma unroll
        for (int j = 0; j < 8; j++) {
            aU[f][j] = (short)f2us((q8[j] + pu8[j]) * 0.125f);
            aV[f][j] = (short)f2us((q8[j] + pv8[j]) * 0.125f);
        }
    }

    // ---- AC scores: S[32] covers 512 cols (s)
    f32x4 S[32];
    #pragma unroll
    for (int ct = 0; ct < 32; ct++) { S[ct][0] = 0.f; S[ct][1] = 0.f; S[ct][2] = 0.f; S[ct][3] = 0.f; }
    const u16* kbase = kB + ((bh * TT) << 6) + quad * 8;
    #pragma unroll
    for (int ct = 0; ct < 32; ct++) {
        const u16* kp = kbase + ((size_t)(ct * 16 + l16) << 6);
        bf16x8 b0 = *(const bf16x8*)kp;
        bf16x8 b1 = *(const bf16x8*)(kp + 32);
        S[ct] = MFMA16(aU[0], b0, S[ct]);
        S[ct] = MFMA16(aU[1], b1, S[ct]);
    }

    // ---- BD: 8 chunks of 64 cols; per-wave 16x80 tile via LDS, skewed gather
    const u16* pbaseh = pB + ((size_t)h << 16);  // h stride = 1024 rows * 64
    for (int g = 0; g < 8; g++) {
        const int pb = g * 64 - t0 + 496 - w * 16;  // P row for c_local=0 (>=0, <=944)
        #pragma unroll
        for (int c5 = 0; c5 < 5; c5++) {
            const u16* pp = pbaseh + ((size_t)(pb + c5 * 16 + l16) << 6) + quad * 8;
            bf16x8 b0 = *(const bf16x8*)pp;
            bf16x8 b1 = *(const bf16x8*)(pp + 32);
            f32x4 c; c[0] = 0.f; c[1] = 0.f; c[2] = 0.f; c[3] = 0.f;
            c = MFMA16(aV[0], b0, c);
            c = MFMA16(aV[1], b1, c);
            #pragma unroll
            for (int r = 0; r < 4; r++)
                bdw[(quad * 4 + r) * 84 + c5 * 16 + l16] = c[r];
        }
        WAVE_SYNC();   // per-wave write->read visibility; WAR handled by in-order DS
        #pragma unroll
        for (int f = 0; f < 4; f++) {
            const int sc = f * 16 + l16;
            #pragma unroll
            for (int r = 0; r < 4; r++) {
                const int local = quad * 4 + r;
                // bd[local][sc + 15 - local]
                S[g * 4 + f][r] += bdw[local * 83 + sc + 15];
            }
        }
    }

    // ---- mask (bit test, no memory traffic)
    #pragma unroll
    for (int ct = 0; ct < 32; ct++) {
        #pragma unroll
        for (int r = 0; r < 4; r++) {
            if (!(mrow[r] & (1u << ct))) S[ct][r] = -100000.0f;
        }
    }

    // ---- softmax (rows live across 16 lanes of this quad)
    float mx[4] = {-3.0e38f, -3.0e38f, -3.0e38f, -3.0e38f};
    float sm[4] = {0.f, 0.f, 0.f, 0.f};
    #pragma unroll
    for (int ct = 0; ct < 32; ct++)
        #pragma unroll
        for (int r = 0; r < 4; r++) mx[r] = fmaxf(mx[r], S[ct][r]);
    #pragma unroll
    for (int r = 0; r < 4; r++)
        #pragma unroll
        for (int off = 1; off < 16; off <<= 1) mx[r] = fmaxf(mx[r], __shfl_xor(mx[r], off, 64));
    #pragma unroll
    for (int ct = 0; ct < 32; ct++)
        #pragma unroll
        for (int r = 0; r < 4; r++) {
            float e = __expf(S[ct][r] - mx[r]);
            S[ct][r] = e;
            sm[r] += e;
        }
    #pragma unroll
    for (int r = 0; r < 4; r++) {
        #pragma unroll
        for (int off = 1; off < 16; off <<= 1) sm[r] += __shfl_xor(sm[r], off, 64);
        sm[r] = 1.0f / sm[r];
    }

    // ---- weights + PV in TWO 256-col passes (LDS halved; measured r14)
    f32x4 Cv[4];
    #pragma unroll
    for (int i = 0; i < 4; i++) { Cv[i][0] = 0.f; Cv[i][1] = 0.f; Cv[i][2] = 0.f; Cv[i][3] = 0.f; }
    const u16* vb0 = vB + ((bh * DKK) << 9) + quad * 8;
    const size_t wbase = (size_t)BB * TT * DD + (((bh * TT + trow)) << 9) + l16;

    #pragma unroll
    for (int p = 0; p < 2; p++) {
        #pragma unroll
        for (int cl = 0; cl < 16; cl++) {
            const int ct = p * 16 + cl;
            #pragma unroll
            for (int r = 0; r < 4; r++) {
                const float wv = S[ct][r] * sm[r];
                wls[w][quad * 4 + r][cl * 16 + l16] = f2us(wv);
                if (!isbf) ((float*)d_out)[wbase + ((size_t)r << 9) + ct * 16] = wv;
            }
        }
        WAVE_SYNC();
        if (isbf) {
            u16* wout = (u16*)d_out + (size_t)BB * TT * DD + ((bh * TT + t0 + w * 16) << 9) + p * 256;
            const int sr = lane >> 5, sc8 = (lane & 31) * 8;
            #pragma unroll
            for (int rr = 0; rr < 8; rr++) {
                bf16x8 vv = *(const bf16x8*)&wls[w][rr * 2 + sr][sc8];
                *(bf16x8*)(wout + ((size_t)(rr * 2 + sr) << 9) + sc8) = vv;
            }
        }
        #pragma unroll
        for (int kl = 0; kl < 8; kl++) {
            const int ks = p * 8 + kl;
            bf16x8 aw = *(const bf16x8*)&wls[w][l16][kl * 32 + quad * 8];
            #pragma unroll
            for (int ctd = 0; ctd < 4; ctd++) {
                const u16* vp = vb0 + ((size_t)(ctd * 16 + l16) << 9) + ks * 32;
                bf16x8 bv = *(const bf16x8*)vp;
                Cv[ctd] = MFMA16(aw, bv, Cv[ctd]);
            }
        }
        WAVE_SYNC();   // drain PV reads before next pass overwrites (order pin)
    }

    // ctx -> ctxB bf16 TOKEN-major [b*T + t][1024] (col = h*64 + d)
    u16* crow = ctxB + ((size_t)(b * TT + trow) << 10) + h * 64 + l16;
    #pragma unroll
    for (int ctd = 0; ctd < 4; ctd++)
        #pragma unroll
        for (int r = 0; r < 4; r++)
            crow[((size_t)r << 10) + ctd * 16] = f2us(Cv[ctd][r]);
}

extern "C" void kernel_launch(void* const* d_in, const int* in_sizes, int n_in,
                              void* d_out, int out_size, void* d_ws, size_t ws_size,
                              hipStream_t stream)
{
    const void* x    = d_in[0];
    const void* mask = d_in[1];
    const void* pos  = d_in[2];
    const void* Wqkv = d_in[3];
    const void* bqkv = d_in[4];
    const void* Wpos = d_in[5];
    const void* posu = d_in[6];
    const void* posv = d_in[7];
    const void* Wout = d_in[8];
    const void* bout = d_in[9];

    char* ws = (char*)d_ws;
    float* qT    = (float*)(ws + 0);                 // [B,H,T,64] f32 16 MiB
    u16*   kB    = (u16*)(ws + 16777216);            // [B,H,T,64] bf16 8 MiB
    u16*   vB    = (u16*)(ws + 25165824);            // [B,H,64,T] bf16 8 MiB (transposed)
    u16*   pB    = (u16*)(ws + 33554432);            // [H,1024,64] bf16 2 MiB
    int*   flags = (int*)(ws + 35651584);
    unsigned int* pmask = (unsigned int*)(ws + 35655680);  // 256 KiB
    u16*   xB    = (u16*)(ws + 35917824);            // [4096,1024] bf16 8 MiB
    u16*   WqkvB = (u16*)(ws + 44306432);            // [3072,1024] bf16 6 MiB
    u16*   WposB = (u16*)(ws + 50597888);            // [1024,1024] bf16 2 MiB
    u16*   posB  = (u16*)(ws + 52695040);            // [1023,1024] bf16 2 MiB
    u16*   WoutB = (u16*)(ws + 54792192);            // [1024,1024] bf16 2 MiB
    u16*   ctxB  = xB;                               // aliases xB (dead after gemm<0>)

    detect_kernel<<<1, 64, 0, stream>>>((const u16*)Wqkv, (const unsigned int*)mask, flags);
    pack_mask<<<dim3(256), 256, 0, stream>>>(mask, pmask, flags);

    // 0) one-shot bf16 conversion of all GEMM inputs (single launch)
    cvt_all<<<dim3(2048), 256, 0, stream>>>(
        x, xB, 4096 * 1024 / 8,
        Wqkv, WqkvB, 3072 * 1024 / 8,
        Wpos, WposB, 1024 * 1024 / 8,
        pos, posB, 1023 * 1024 / 8,
        Wout, WoutB, 1024 * 1024 / 8,
        flags);

    // 1) qkv = x @ Wqkv^T + bqkv -> q(f32 qT), k(kB), v(vB transposed)
    gemm_mfma<0><<<dim3(24, 32), 256, 0, stream>>>(
        xB, WqkvB, bqkv, flags, qT, kB, vB, pB, nullptr, BB * TT, 3 * DD, DD);

    // 2) p = pos @ Wpos^T -> pB
    gemm_mfma<1><<<dim3(8, 8), 256, 0, stream>>>(
        posB, WposB, nullptr, flags, qT, kB, vB, pB, nullptr, SS, DD, DD);

    // 3) attention (b on x => XCD-pinned batches): weights -> d_out, ctx -> ctxB
    attn_mfma<<<dim3(BB, HH, 8), 256, 0, stream>>>(
        qT, kB, vB, pB, posu, posv, pmask, d_out, ctxB, flags);

    // 4) out = ctx @ Wout^T + bout
    gemm_mfma<2><<<dim3(8, 32), 256, 0, stream>>>(
        ctxB, WoutB, bout, flags, qT, kB, vB, pB, d_out, BB * TT, DD, DD);
}